// Round 10
// baseline (1390.837 us; speedup 1.0000x reference)
//
#include <hip/hip_runtime.h>
#include <hip/hip_fp16.h>
#include <cmath>

#define DEV __device__ __forceinline__

typedef unsigned short ushortT;
typedef short bs8 __attribute__((ext_vector_type(8)));
typedef float f32x4 __attribute__((ext_vector_type(4)));
typedef _Float16 f16x2 __attribute__((ext_vector_type(2)));

constexpr int kBW = 4096;          // B*W
constexpr int kM = 100, kF = 8, kN = 33, kH = 256, kGH = 128, kE = 64;

// ws offsets (in floats)
constexpr int OFF_ROWPTR  = 0;       // 34 int
constexpr int OFF_COLSRC  = 64;      // 64 int
constexpr int OFF_COLNORM = 128;     // 64 f
constexpr int OFF_C       = 192;     // 256 f (folded bias)
constexpr int OFF_WC      = 512;     // 128*256 f (post_w@fg_w)
constexpr int OFF_SPRE    = 33280;               // 4096*256 (s_pre -> s0 -> s1)
constexpr int OFF_GI      = OFF_SPRE + kBW * kH; // 4096*768 f
constexpr int OFF_SFUSE   = OFF_GI + kBW * 3 * kH;  // 4096*256 f
constexpr int OFF_SGATE   = OFF_SFUSE + kBW * kH;   // 4096*256 f
// scan weights (f16 pairs) live in SFUSE region (dead until k_fsgate):
constexpr int OFF_WQ0     = OFF_SFUSE;            // 98304 u32
constexpr int OFF_WQ1     = OFF_SFUSE + 98304;    // 98304 u32
// bf16 B-fragment weights for k_fused live in GI region (dead after scans):
constexpr int WB_TW1  = 0;        // 4*128*128
constexpr int WB_TW2  = 65536;    // 4*128*128
constexpr int WB_WC   = 131072;   // 256 cols x 128 k
constexpr int WB_GATE = 163840;   // 256 cols x 256 k
constexpr int WB_D1   = 229376;   // 256 cols x 256 k
constexpr int WB_TOT  = 294912;

DEV float frcp(float x) { return __builtin_amdgcn_rcpf(x); }
DEV float fsig(float x) { return frcp(1.0f + __expf(-x)); }
DEV float ftanh(float x) { float e = __expf(2.0f * x); return 1.0f - 2.0f * frcp(e + 1.0f); }

DEV ushortT f2bf(float x) {
  unsigned u = __float_as_uint(x);
  unsigned r = u + 0x7fffu + ((u >> 16) & 1u);
  return (ushortT)(r >> 16);
}
DEV float bf2f(ushortT u) { return __uint_as_float(((unsigned)u) << 16); }

DEV f32x4 mfma16(bs8 a, bs8 b, f32x4 c) {
  return __builtin_amdgcn_mfma_f32_16x16x32_bf16(a, b, c, 0, 0, 0);
}
DEV bs8 ldb(const ushortT* p) { return *reinterpret_cast<const bs8*>(p); }

#if __has_builtin(__builtin_amdgcn_fdot2)
DEV float dot2(unsigned w, unsigned hp, float acc) {
  f16x2 wv = __builtin_bit_cast(f16x2, w);
  f16x2 hv = __builtin_bit_cast(f16x2, hp);
  return __builtin_amdgcn_fdot2(wv, hv, acc, false);
}
#else
DEV float dot2(unsigned w, unsigned hp, float acc) {
  f16x2 wv = __builtin_bit_cast(f16x2, w);
  f16x2 hv = __builtin_bit_cast(f16x2, hp);
  acc = fmaf((float)wv.x, (float)hv.x, acc);
  acc = fmaf((float)wv.y, (float)hv.y, acc);
  return acc;
}
#endif

// ---------------- graph prep: degree norm + CSR by dst ---------------------------
__global__ void k_prep(const int* __restrict__ ei, const float* __restrict__ ew,
                       float* __restrict__ ws) {
  if (blockIdx.x != 0 || threadIdx.x != 0) return;
  int* rowptr = (int*)(ws + OFF_ROWPTR);
  int* colsrc = (int*)(ws + OFF_COLSRC);
  float* colnorm = ws + OFF_COLNORM;
  const int* src = ei;
  const int* dst = ei + kE;
  float deg[kN]; int cnt[kN];
  for (int n = 0; n < kN; ++n) { deg[n] = 0.f; cnt[n] = 0; }
  for (int e = 0; e < kE; ++e) { deg[dst[e]] += ew[e]; cnt[dst[e]]++; }
  float dinv[kN];
  for (int n = 0; n < kN; ++n) dinv[n] = deg[n] > 0.f ? 1.0f / sqrtf(deg[n]) : 0.f;
  int pos[kN];
  int run = 0;
  for (int n = 0; n < kN; ++n) { rowptr[n] = run; pos[n] = run; run += cnt[n]; }
  rowptr[kN] = run;
  for (int e = 0; e < kE; ++e) {
    int d = dst[e];
    int p = pos[d]++;
    colsrc[p] = src[e];
    colnorm[p] = dinv[src[e]] * ew[e] * dinv[d];
  }
}

// ---------------- fold Wc = post_w @ fg_w (128x256), c = post_b @ fg_w + fg_b -----
__global__ void k_wcfold(const float* __restrict__ post_w, const float* __restrict__ post_b,
                         const float* __restrict__ fg_w, const float* __restrict__ fg_b,
                         float* __restrict__ ws) {
  const int j = threadIdx.x;
  if ((int)blockIdx.x < kGH) {
    const int k = blockIdx.x;
    float a = 0.f;
    #pragma unroll 4
    for (int m = 0; m < kH; ++m) a = fmaf(post_w[k * kH + m], fg_w[m * kH + j], a);
    ws[OFF_WC + k * kH + j] = a;
  } else {
    float a = fg_b[j];
    #pragma unroll 4
    for (int m = 0; m < kH; ++m) a = fmaf(post_b[m], fg_w[m * kH + j], a);
    ws[OFF_C + j] = a;
  }
}

// ---------------- scan weights: whh[k][j] -> f16 pairs wq[(k/2)*768 + j] ----------
__global__ void k_wq(const float* __restrict__ w0, const float* __restrict__ w1,
                     float* __restrict__ ws) {
  const int idx = blockIdx.x * 256 + threadIdx.x;
  if (idx >= 2 * 98304) return;
  const int layer = idx / 98304;
  const int rem = idx - layer * 98304;
  const int p = rem / 768, j = rem - p * 768;
  const float* w = layer ? w1 : w0;
  unsigned* dst = (unsigned*)(ws + (layer ? OFF_WQ1 : OFF_WQ0));
  __half2 v = __floats2half2_rn(w[(2 * p) * 768 + j], w[(2 * p + 1) * 768 + j]);
  dst[rem] = *reinterpret_cast<unsigned*>(&v);
}

// ---------------- bf16 B-fragment weights ([col][k]) for k_fused -----------------
__global__ void k_wprep(const float* __restrict__ tw1, const float* __restrict__ tw2,
                        const float* __restrict__ gatew, const float* __restrict__ d1w,
                        float* __restrict__ ws) {
  const int idx = blockIdx.x * 256 + threadIdx.x;
  if (idx >= WB_TOT) return;
  ushortT* WB = (ushortT*)(ws + OFF_GI);
  float v; int dst;
  if (idx < 65536) {
    int s = idx >> 14, r = idx & 16383, k = r >> 7, col = r & 127;
    v = tw1[(s << 14) + (k << 7) + col]; dst = WB_TW1 + (s << 14) + (col << 7) + k;
  } else if (idx < 131072) {
    int i = idx - 65536; int s = i >> 14, r = i & 16383, k = r >> 7, col = r & 127;
    v = tw2[(s << 14) + (k << 7) + col]; dst = WB_TW2 + (s << 14) + (col << 7) + k;
  } else if (idx < 163840) {
    int i = idx - 131072; int k = i & 127, col = i >> 7;
    v = ws[OFF_WC + (k << 8) + col]; dst = WB_WC + (col << 7) + k;
  } else if (idx < 229376) {
    int i = idx - 163840; int k = i & 255, col = i >> 8;
    v = gatew[(k << 8) + col]; dst = WB_GATE + (col << 8) + k;
  } else {
    int i = idx - 229376; int k = i & 255, col = i >> 8;
    v = d1w[(k << 8) + col]; dst = WB_D1 + (col << 8) + k;
  }
  WB[dst] = f2bf(v);
}

// ---------------- temporal pre-MLP, 16 rows per block -----------------------------
__global__ __launch_bounds__(256) void k_tpmlp(
    const float* __restrict__ r_seq, const float* __restrict__ x_wls,
    const float* __restrict__ w1, const float* __restrict__ b1,
    const float* __restrict__ w2, const float* __restrict__ b2,
    float* __restrict__ sout) {
  __shared__ float inr[16][kM + 2 * kN];  // 16 x 166
  __shared__ float h1[16][kH];
  const int bw0 = blockIdx.x * 16, tid = threadIdx.x;
  #pragma unroll
  for (int r = 0; r < 16; ++r) {
    for (int c = tid; c < kM + 2 * kN; c += 256)
      inr[r][c] = (c < kM) ? r_seq[(bw0 + r) * kM + c]
                           : x_wls[(bw0 + r) * 2 * kN + (c - kM)];
  }
  __syncthreads();
  float acc[16];
  {
    const float bb = b1[tid];
    #pragma unroll
    for (int r = 0; r < 16; ++r) acc[r] = bb;
  }
  for (int k = 0; k < kM + 2 * kN; ++k) {
    const float w = w1[k * kH + tid];
    #pragma unroll
    for (int r = 0; r < 16; ++r) acc[r] = fmaf(inr[r][k], w, acc[r]);
  }
  #pragma unroll
  for (int r = 0; r < 16; ++r) h1[r][tid] = fmaxf(acc[r], 0.f);
  __syncthreads();
  {
    const float bb = b2[tid];
    #pragma unroll
    for (int r = 0; r < 16; ++r) acc[r] = bb;
  }
  #pragma unroll 2
  for (int k = 0; k < kH; ++k) {
    const float w = w2[k * kH + tid];
    #pragma unroll
    for (int r = 0; r < 16; ++r) acc[r] = fmaf(h1[r][k], w, acc[r]);
  }
  #pragma unroll
  for (int r = 0; r < 16; ++r) sout[(bw0 + r) * kH + tid] = fmaxf(acc[r], 0.f);
}

// ---------------- gi = s @ wih + bih, 16 rows per block ---------------------------
__global__ __launch_bounds__(768) void k_gigemm(
    const float* __restrict__ sin, const float* __restrict__ wih,
    const float* __restrict__ bih, float* __restrict__ gi) {
  __shared__ float sr[16][kH];
  const int bw0 = blockIdx.x * 16, tid = threadIdx.x;
  for (int i = tid; i < 16 * kH; i += 768) sr[i >> 8][i & 255] = sin[bw0 * kH + i];
  __syncthreads();
  float acc[16];
  {
    const float bb = bih[tid];
    #pragma unroll
    for (int r = 0; r < 16; ++r) acc[r] = bb;
  }
  #pragma unroll 2
  for (int k = 0; k < kH; ++k) {
    const float w = wih[k * 768 + tid];
    #pragma unroll
    for (int r = 0; r < 16; ++r) acc[r] = fmaf(sr[r][k], w, acc[r]);
  }
  #pragma unroll
  for (int r = 0; r < 16; ++r) gi[(bw0 + r) * 768 + tid] = acc[r];
}

// ---------------- GRU scan: pair-split columns, weights in VGPRs (R9, kept) -------
__global__ __launch_bounds__(512, 2) void k_scan(
    const float* __restrict__ gi, const float* __restrict__ wq,
    const float* __restrict__ bhh, float* __restrict__ sout) {
  __shared__ __align__(16) unsigned hpk[2][kH / 2];
  const int b = blockIdx.x, tid = threadIdx.x;
  const int c = tid >> 1, hh = tid & 1;
  const unsigned* wqp = (const unsigned*)wq + hh * 64 * 768 + c;
  unsigned wA[64], wB[64], wC[64];
  #pragma unroll
  for (int p = 0; p < 64; ++p) {
    wA[p] = wqp[p * 768];
    wB[p] = wqp[p * 768 + 256];
    wC[p] = wqp[p * 768 + 512];
  }
  const float bR = bhh[c], bZ = bhh[kH + c], bN = bhh[2 * kH + c];
  if (tid < kH / 2) hpk[0][tid] = 0u;
  float h = 0.f;
  __syncthreads();
  const float* gbase = gi + b * 128 * 768 + c;
  for (int t = 0; t < 128; ++t) {
    const float* g = gbase + t * 768;
    const float gA = g[0], gB = g[256], gC = g[512];
    float aR0 = 0.f, aR1 = 0.f, aZ0 = 0.f, aZ1 = 0.f, aN0 = 0.f, aN1 = 0.f;
    const unsigned* hb = hpk[t & 1] + hh * 64;
    #pragma unroll
    for (int q = 0; q < 16; ++q) {
      const uint4 hp = *reinterpret_cast<const uint4*>(hb + 4 * q);
      aR0 = dot2(wA[4 * q + 0], hp.x, aR0);
      aZ0 = dot2(wB[4 * q + 0], hp.x, aZ0);
      aN0 = dot2(wC[4 * q + 0], hp.x, aN0);
      aR1 = dot2(wA[4 * q + 1], hp.y, aR1);
      aZ1 = dot2(wB[4 * q + 1], hp.y, aZ1);
      aN1 = dot2(wC[4 * q + 1], hp.y, aN1);
      aR0 = dot2(wA[4 * q + 2], hp.z, aR0);
      aZ0 = dot2(wB[4 * q + 2], hp.z, aZ0);
      aN0 = dot2(wC[4 * q + 2], hp.z, aN0);
      aR1 = dot2(wA[4 * q + 3], hp.w, aR1);
      aZ1 = dot2(wB[4 * q + 3], hp.w, aZ1);
      aN1 = dot2(wC[4 * q + 3], hp.w, aN1);
    }
    float aR = aR0 + aR1; aR += __shfl_xor(aR, 1, 64);
    float aZ = aZ0 + aZ1; aZ += __shfl_xor(aZ, 1, 64);
    float aN = aN0 + aN1; aN += __shfl_xor(aN, 1, 64);
    const float r = fsig(gA + bR + aR);
    const float z = fsig(gB + bZ + aZ);
    const float n = ftanh(fmaf(r, aN + bN, gC));
    h = (1.f - z) * n + z * h;
    if (hh == 0) reinterpret_cast<__half*>(hpk[(t + 1) & 1])[c] = __float2half(h);
    else sout[(b * 128 + t) * kH + c] = h;
    __syncthreads();
  }
}

// ---------------- sfuse/sgate, 16 rows per block ----------------------------------
__global__ __launch_bounds__(256) void k_fsgate(
    const float* __restrict__ s1, const float* __restrict__ fsw,
    const float* __restrict__ fsb, const float* __restrict__ gw,
    const float* __restrict__ gb, float* __restrict__ sfuse,
    float* __restrict__ sgate) {
  __shared__ float sr[16][kH], sf[16][kH];
  const int bw0 = blockIdx.x * 16, tid = threadIdx.x;
  for (int i = tid; i < 16 * kH; i += 256) sr[i >> 8][i & 255] = s1[bw0 * kH + i];
  __syncthreads();
  float acc[16];
  {
    const float bb = fsb[tid];
    #pragma unroll
    for (int r = 0; r < 16; ++r) acc[r] = bb;
  }
  #pragma unroll 2
  for (int k = 0; k < kH; ++k) {
    const float w = fsw[k * kH + tid];
    #pragma unroll
    for (int r = 0; r < 16; ++r) acc[r] = fmaf(sr[r][k], w, acc[r]);
  }
  #pragma unroll
  for (int r = 0; r < 16; ++r) { sf[r][tid] = acc[r]; sfuse[(bw0 + r) * kH + tid] = acc[r]; }
  __syncthreads();
  {
    const float bb = gb[tid];
    #pragma unroll
    for (int r = 0; r < 16; ++r) acc[r] = bb;
  }
  #pragma unroll 2
  for (int k = 0; k < kH; ++k) {
    const float w = gw[(kH + k) * kH + tid];
    #pragma unroll
    for (int r = 0; r < 16; ++r) acc[r] = fmaf(sf[r][k], w, acc[r]);
  }
  #pragma unroll
  for (int r = 0; r < 16; ++r) sgate[(bw0 + r) * kH + tid] = acc[r];
}

// ================= fused GNN + gate + decoder: 2 GRAPHS PER BLOCK ================
// 512 threads = 8 waves, grid 2048. Each block processes graphs bw0, bw0+1.
// B-fragment (bb) loads SHARED across both graphs (halves L2 load events; 2x
// MFMA per load hides its latency). acc[2][...] fully static-unrolled.
// Bank-conflict fix: buf stride 132 ushorts (66 dwords == 2 mod 32), GT stride
// 260 (130 dwords == 2 mod 32) — was 136/264 (== 4 mod 32, 4-way conflicts).
// Arena per graph: buf0[36x132] | buf1[36x132] = 9504 ushorts; GT[36x260]=9360
// overlaps buf0+buf1 (reads -> barrier -> overwrite; accs in regs).

constexpr int BSTR = 132;               // buf row stride (ushorts)
constexpr int GSTR = 260;               // GT row stride (ushorts)
constexpr int SB0 = 0;
constexpr int SB1 = 36 * BSTR;          // 4752
constexpr int ASTR = 2 * 36 * BSTR;     // 9504 per-graph arena

// both graphs: dst(rows<33) = P @ src, bf16 pairs
DEV void propb2(ushortT* __restrict__ S, int dstoff, int srcoff,
                const int* __restrict__ rp, const int* __restrict__ cs,
                const float* __restrict__ cn) {
  for (int idx = threadIdx.x; idx < 2 * kN * 66; idx += 512) {
    const int g = idx >= kN * 66;
    const int r = idx - g * (kN * 66);
    const int n = r / 66, j2 = r - n * 66;
    ushortT* base = S + g * ASTR;
    float a0 = 0.f, a1 = 0.f;
    const int p1 = rp[n + 1];
    for (int p = rp[n]; p < p1; ++p) {
      const unsigned v = *(const unsigned*)(base + srcoff + cs[p] * BSTR + 2 * j2);
      const float w = cn[p];
      a0 = fmaf(__uint_as_float(v << 16), w, a0);
      a1 = fmaf(__uint_as_float(v & 0xffff0000u), w, a1);
    }
    *(unsigned*)(base + dstoff + n * BSTR + 2 * j2) =
        (unsigned)f2bf(a0) | ((unsigned)f2bf(a1) << 16);
  }
}

// tag pass over both graphs: buf0 -> buf0, ping-pong buf1. bb shared across g.
template <bool RELU>
DEV void tag_mfma2(ushortT* __restrict__ S, const ushortT* __restrict__ WT,
                   const float* __restrict__ b, const int* __restrict__ rp,
                   const int* __restrict__ cs, const float* __restrict__ cn,
                   int wv, int lane) {
  const int lr = lane & 15, lg = lane >> 4;
  const int col = wv * 16 + lr;
  f32x4 accA[3], accB[3];
  #pragma unroll
  for (int i = 0; i < 3; ++i) { accA[i] = (f32x4){0.f,0.f,0.f,0.f}; accB[i] = (f32x4){0.f,0.f,0.f,0.f}; }
  #pragma unroll
  for (int s = 0; s < 4; ++s) {
    const int aoff = (s & 1) ? SB1 : SB0;
    const int noff = (s & 1) ? SB0 : SB1;
    #pragma unroll
    for (int ks = 0; ks < 4; ++ks) {
      const int kof = ks * 32 + lg * 8;
      bs8 bb = ldb(WT + (s << 14) + (col << 7) + kof);
      {
        const ushortT* A = S + aoff;
        bs8 a0 = ldb(A + lr * BSTR + kof);
        bs8 a1 = ldb(A + (16 + lr) * BSTR + kof);
        bs8 a2 = ldb(A + (32 + lr) * BSTR + kof);
        accA[0] = mfma16(a0, bb, accA[0]);
        accA[1] = mfma16(a1, bb, accA[1]);
        accA[2] = mfma16(a2, bb, accA[2]);
      }
      {
        const ushortT* A = S + ASTR + aoff;
        bs8 a0 = ldb(A + lr * BSTR + kof);
        bs8 a1 = ldb(A + (16 + lr) * BSTR + kof);
        bs8 a2 = ldb(A + (32 + lr) * BSTR + kof);
        accB[0] = mfma16(a0, bb, accB[0]);
        accB[1] = mfma16(a1, bb, accB[1]);
        accB[2] = mfma16(a2, bb, accB[2]);
      }
    }
    if (s < 3) {
      propb2(S, noff, aoff, rp, cs, cn);
      __syncthreads();
    }
  }
  __syncthreads();  // all s=3 A-reads complete before overwriting buf0
  const float bias = b[col];
  #pragma unroll
  for (int mt = 0; mt < 3; ++mt)
    #pragma unroll
    for (int r = 0; r < 4; ++r) {
      const int row = mt * 16 + lg * 4 + r;
      if (row < kN) {
        float x0 = accA[mt][r] + bias;
        float x1 = accB[mt][r] + bias;
        if (RELU) { x0 = fmaxf(x0, 0.f); x1 = fmaxf(x1, 0.f); }
        (S + SB0)[row * BSTR + col] = f2bf(x0);
        (S + ASTR + SB0)[row * BSTR + col] = f2bf(x1);
      }
    }
  __syncthreads();
}

__global__ __launch_bounds__(512, 2) void k_fused(
    const float* __restrict__ feat_seq, const float* __restrict__ x_wls,
    const float* __restrict__ pre_w, const float* __restrict__ pre_b,
    const float* __restrict__ tb1, const float* __restrict__ tb2,
    const float* __restrict__ d1b, const float* __restrict__ d2w,
    const float* __restrict__ d2b, const float* __restrict__ ws,
    const float* __restrict__ sfuse, const float* __restrict__ sgate,
    float* __restrict__ out) {
  __shared__ __align__(16) ushortT S[2 * ASTR];    // 38016 B
  __shared__ float sfrow[2][kH], sgrow[2][kH];
  __shared__ float xw[2][2 * kN];
  __shared__ float featl[2][kF];
  __shared__ int rp[kN + 1], cs[kE];
  __shared__ float cn[kE];
  __shared__ float part[2][8][48][2];
  const int tid = threadIdx.x, bw0 = blockIdx.x * 2;
  const int wv = tid >> 6, lane = tid & 63;
  const int lr = lane & 15, lg = lane >> 4;
  const ushortT* WB = (const ushortT*)(ws + OFF_GI);

  {
    const int g = tid >> 8, j = tid & 255;
    sfrow[g][j] = sfuse[(bw0 + g) * kH + j];
    sgrow[g][j] = sgate[(bw0 + g) * kH + j];
  }
  if (tid < 132) {
    const int g = tid >= 66;
    const int i = tid - g * 66;
    xw[g][i] = x_wls[(bw0 + g) * 2 * kN + i];
  } else if (tid >= 132 && tid < 148) {
    const int i = tid - 132, g = i >> 3;
    featl[g][i & 7] = feat_seq[(bw0 + g) * kF + (i & 7)];
  }
  if (tid >= 192 && tid < 192 + kN + 1) rp[tid - 192] = ((const int*)(ws + OFF_ROWPTR))[tid - 192];
  if (tid >= 256 && tid < 320) {
    cs[tid - 256] = ((const int*)(ws + OFF_COLSRC))[tid - 256];
    cn[tid - 256] = ws[OFF_COLNORM + (tid - 256)];
  }
  // zero pad rows 33..35 of both bufs, both graphs
  if (tid < 3 * BSTR) {
    S[SB0 + kN * BSTR + tid] = 0;
    S[SB1 + kN * BSTR + tid] = 0;
    S[ASTR + SB0 + kN * BSTR + tid] = 0;
    S[ASTR + SB1 + kN * BSTR + tid] = 0;
  }
  __syncthreads();

  // gin for both graphs -> buf0 (33x128 bf16)
  #pragma unroll
  for (int g = 0; g < 2; ++g) {
    ushortT* B0 = S + g * ASTR + SB0;
    for (int idx = tid; idx < kN * kGH; idx += 512) {
      const int n = idx >> 7, j = idx & 127;
      float a = pre_b[j];
      #pragma unroll
      for (int f = 0; f < kF; ++f) a = fmaf(featl[g][f], pre_w[f * kGH + j], a);
      a = fmaf(xw[g][n], pre_w[8 * kGH + j], a);
      a = fmaf(xw[g][kN + n], pre_w[9 * kGH + j], a);
      B0[n * BSTR + j] = f2bf(a);
    }
  }
  __syncthreads();

  tag_mfma2<true >(S, WB + WB_TW1, tb1, rp, cs, cn, wv, lane);
  tag_mfma2<false>(S, WB + WB_TW2, tb2, rp, cs, cn, wv, lane);

  // ---- g_t = G @ Wc + c -> GT (33x256 bf16) per graph, regs then overwrite ----
  {
    f32x4 accA[6], accB[6];
    #pragma unroll
    for (int i = 0; i < 6; ++i) { accA[i] = (f32x4){0.f,0.f,0.f,0.f}; accB[i] = (f32x4){0.f,0.f,0.f,0.f}; }
    #pragma unroll
    for (int ks = 0; ks < 4; ++ks) {
      const int kof = ks * 32 + lg * 8;
      const int c0 = (wv * 2 + 0) * 16 + lr, c1 = (wv * 2 + 1) * 16 + lr;
      bs8 bb0 = ldb(WB + WB_WC + (c0 << 7) + kof);
      bs8 bb1 = ldb(WB + WB_WC + (c1 << 7) + kof);
      {
        const ushortT* A = S + SB0;
        bs8 a0 = ldb(A + lr * BSTR + kof);
        bs8 a1 = ldb(A + (16 + lr) * BSTR + kof);
        bs8 a2 = ldb(A + (32 + lr) * BSTR + kof);
        accA[0] = mfma16(a0, bb0, accA[0]); accA[1] = mfma16(a0, bb1, accA[1]);
        accA[2] = mfma16(a1, bb0, accA[2]); accA[3] = mfma16(a1, bb1, accA[3]);
        accA[4] = mfma16(a2, bb0, accA[4]); accA[5] = mfma16(a2, bb1, accA[5]);
      }
      {
        const ushortT* A = S + ASTR + SB0;
        bs8 a0 = ldb(A + lr * BSTR + kof);
        bs8 a1 = ldb(A + (16 + lr) * BSTR + kof);
        bs8 a2 = ldb(A + (32 + lr) * BSTR + kof);
        accB[0] = mfma16(a0, bb0, accB[0]); accB[1] = mfma16(a0, bb1, accB[1]);
        accB[2] = mfma16(a1, bb0, accB[2]); accB[3] = mfma16(a1, bb1, accB[3]);
        accB[4] = mfma16(a2, bb0, accB[4]); accB[5] = mfma16(a2, bb1, accB[5]);
      }
    }
    __syncthreads();  // all buf reads done; arenas become GT
    #pragma unroll
    for (int nt = 0; nt < 2; ++nt) {
      const int col = (wv * 2 + nt) * 16 + lr;
      const float cb = ws[OFF_C + col];
      #pragma unroll
      for (int mt = 0; mt < 3; ++mt)
        #pragma unroll
        for (int r = 0; r < 4; ++r) {
          const int row = mt * 16 + lg * 4 + r;
          if (row < kN) {
            S[row * GSTR + col] = f2bf(accA[mt * 2 + nt][r] + cb);
            (S + ASTR)[row * GSTR + col] = f2bf(accB[mt * 2 + nt][r] + cb);
          }
        }
    }
    __syncthreads();
  }

  // ---- gate: alpha = sigmoid(GT @ gate_w + sgate); U = a*gt+(1-a)*sfuse -> GT ----
  {
    f32x4 accA[6], accB[6];
    #pragma unroll
    for (int i = 0; i < 6; ++i) { accA[i] = (f32x4){0.f,0.f,0.f,0.f}; accB[i] = (f32x4){0.f,0.f,0.f,0.f}; }
    #pragma unroll 2
    for (int ks = 0; ks < 8; ++ks) {
      const int kof = ks * 32 + lg * 8;
      const int r2 = (32 + lr) < 36 ? (32 + lr) : 35;
      const int c0 = (wv * 2 + 0) * 16 + lr, c1 = (wv * 2 + 1) * 16 + lr;
      bs8 bb0 = ldb(WB + WB_GATE + (c0 << 8) + kof);
      bs8 bb1 = ldb(WB + WB_GATE + (c1 << 8) + kof);
      {
        const ushortT* A = S;
        bs8 a0 = ldb(A + lr * GSTR + kof);
        bs8 a1 = ldb(A + (16 + lr) * GSTR + kof);
        bs8 a2 = ldb(A + r2 * GSTR + kof);
        accA[0] = mfma16(a0, bb0, accA[0]); accA[1] = mfma16(a0, bb1, accA[1]);
        accA[2] = mfma16(a1, bb0, accA[2]); accA[3] = mfma16(a1, bb1, accA[3]);
        accA[4] = mfma16(a2, bb0, accA[4]); accA[5] = mfma16(a2, bb1, accA[5]);
      }
      {
        const ushortT* A = S + ASTR;
        bs8 a0 = ldb(A + lr * GSTR + kof);
        bs8 a1 = ldb(A + (16 + lr) * GSTR + kof);
        bs8 a2 = ldb(A + r2 * GSTR + kof);
        accB[0] = mfma16(a0, bb0, accB[0]); accB[1] = mfma16(a0, bb1, accB[1]);
        accB[2] = mfma16(a1, bb0, accB[2]); accB[3] = mfma16(a1, bb1, accB[3]);
        accB[4] = mfma16(a2, bb0, accB[4]); accB[5] = mfma16(a2, bb1, accB[5]);
      }
    }
    // U into accs (reads GT), barrier, write U over GT
    #pragma unroll
    for (int nt = 0; nt < 2; ++nt) {
      const int col = (wv * 2 + nt) * 16 + lr;
      const float sg0 = sgrow[0][col], sf0 = sfrow[0][col];
      const float sg1 = sgrow[1][col], sf1 = sfrow[1][col];
      #pragma unroll
      for (int mt = 0; mt < 3; ++mt)
        #pragma unroll
        for (int r = 0; r < 4; ++r) {
          const int row = mt * 16 + lg * 4 + r;
          if (row < kN) {
            const float al0 = fsig(accA[mt * 2 + nt][r] + sg0);
            const float gt0 = bf2f(S[row * GSTR + col]);
            accA[mt * 2 + nt][r] = al0 * gt0 + (1.f - al0) * sf0;
            const float al1 = fsig(accB[mt * 2 + nt][r] + sg1);
            const float gt1 = bf2f((S + ASTR)[row * GSTR + col]);
            accB[mt * 2 + nt][r] = al1 * gt1 + (1.f - al1) * sf1;
          }
        }
    }
    __syncthreads();
    #pragma unroll
    for (int nt = 0; nt < 2; ++nt) {
      const int col = (wv * 2 + nt) * 16 + lr;
      #pragma unroll
      for (int mt = 0; mt < 3; ++mt)
        #pragma unroll
        for (int r = 0; r < 4; ++r) {
          const int row = mt * 16 + lg * 4 + r;
          if (row < kN) {
            S[row * GSTR + col] = f2bf(accA[mt * 2 + nt][r]);
            (S + ASTR)[row * GSTR + col] = f2bf(accB[mt * 2 + nt][r]);
          }
        }
    }
    __syncthreads();
  }

  // ---- d1: V = relu(U @ d1w + d1b); d2 (256->2) + residual ----
  {
    f32x4 accA[6], accB[6];
    #pragma unroll
    for (int i = 0; i < 6; ++i) { accA[i] = (f32x4){0.f,0.f,0.f,0.f}; accB[i] = (f32x4){0.f,0.f,0.f,0.f}; }
    #pragma unroll 2
    for (int ks = 0; ks < 8; ++ks) {
      const int kof = ks * 32 + lg * 8;
      const int r2 = (32 + lr) < 36 ? (32 + lr) : 35;
      const int c0 = (wv * 2 + 0) * 16 + lr, c1 = (wv * 2 + 1) * 16 + lr;
      bs8 bb0 = ldb(WB + WB_D1 + (c0 << 8) + kof);
      bs8 bb1 = ldb(WB + WB_D1 + (c1 << 8) + kof);
      {
        const ushortT* A = S;
        bs8 a0 = ldb(A + lr * GSTR + kof);
        bs8 a1 = ldb(A + (16 + lr) * GSTR + kof);
        bs8 a2 = ldb(A + r2 * GSTR + kof);
        accA[0] = mfma16(a0, bb0, accA[0]); accA[1] = mfma16(a0, bb1, accA[1]);
        accA[2] = mfma16(a1, bb0, accA[2]); accA[3] = mfma16(a1, bb1, accA[3]);
        accA[4] = mfma16(a2, bb0, accA[4]); accA[5] = mfma16(a2, bb1, accA[5]);
      }
      {
        const ushortT* A = S + ASTR;
        bs8 a0 = ldb(A + lr * GSTR + kof);
        bs8 a1 = ldb(A + (16 + lr) * GSTR + kof);
        bs8 a2 = ldb(A + r2 * GSTR + kof);
        accB[0] = mfma16(a0, bb0, accB[0]); accB[1] = mfma16(a0, bb1, accB[1]);
        accB[2] = mfma16(a1, bb0, accB[2]); accB[3] = mfma16(a1, bb1, accB[3]);
        accB[4] = mfma16(a2, bb0, accB[4]); accB[5] = mfma16(a2, bb1, accB[5]);
      }
    }
    // per-graph sequential epilogue (reuses p-regs)
    #pragma unroll
    for (int g = 0; g < 2; ++g) {
      float p0[3][4], p1[3][4];
      #pragma unroll
      for (int mt = 0; mt < 3; ++mt)
        #pragma unroll
        for (int r = 0; r < 4; ++r) { p0[mt][r] = 0.f; p1[mt][r] = 0.f; }
      #pragma unroll
      for (int nt = 0; nt < 2; ++nt) {
        const int col = (wv * 2 + nt) * 16 + lr;
        const float db = d1b[col];
        const float2 dp = *reinterpret_cast<const float2*>(d2w + col * 2);
        #pragma unroll
        for (int mt = 0; mt < 3; ++mt)
          #pragma unroll
          for (int r = 0; r < 4; ++r) {
            const float av = g == 0 ? accA[mt * 2 + nt][r] : accB[mt * 2 + nt][r];
            const float v = fmaxf(av + db, 0.f);
            p0[mt][r] = fmaf(v, dp.x, p0[mt][r]);
            p1[mt][r] = fmaf(v, dp.y, p1[mt][r]);
          }
      }
      #pragma unroll
      for (int mt = 0; mt < 3; ++mt)
        #pragma unroll
        for (int r = 0; r < 4; ++r) {
          #pragma unroll
          for (int off = 1; off < 16; off <<= 1) {
            p0[mt][r] += __shfl_xor(p0[mt][r], off, 64);
            p1[mt][r] += __shfl_xor(p1[mt][r], off, 64);
          }
        }
      if (lr == 0) {
        #pragma unroll
        for (int mt = 0; mt < 3; ++mt)
          #pragma unroll
          for (int r = 0; r < 4; ++r) {
            const int row = mt * 16 + lg * 4 + r;
            part[g][wv][row][0] = p0[mt][r];
            part[g][wv][row][1] = p1[mt][r];
          }
      }
    }
    __syncthreads();
    if (tid < 132) {
      const int g = tid >= 66;
      const int i = tid - g * 66;
      const int c = i >= 33 ? 1 : 0;
      const int n = i - 33 * c;
      float sv = d2b[c];
      #pragma unroll
      for (int w = 0; w < 8; ++w) sv += part[g][w][n][c];
      out[(bw0 + g) * 66 + i] = xw[g][i] + sv;
    }
  }
}

extern "C" void kernel_launch(void* const* d_in, const int* in_sizes, int n_in,
                              void* d_out, int out_size, void* d_ws, size_t ws_size,
                              hipStream_t stream) {
  const float* r_seq  = (const float*)d_in[0];
  const float* feat   = (const float*)d_in[1];
  const float* x_wls  = (const float*)d_in[2];
  const int*   eidx   = (const int*)d_in[3];
  const float* ew     = (const float*)d_in[4];
  const float* pre_w  = (const float*)d_in[5];
  const float* pre_b  = (const float*)d_in[6];
  const float* tag_w1 = (const float*)d_in[7];
  const float* tag_b1 = (const float*)d_in[8];
  const float* tag_w2 = (const float*)d_in[9];
  const float* tag_b2 = (const float*)d_in[10];
  const float* post_w = (const float*)d_in[11];
  const float* post_b = (const float*)d_in[12];
  const float* tp_w1  = (const float*)d_in[13];
  const float* tp_b1  = (const float*)d_in[14];
  const float* tp_w2  = (const float*)d_in[15];
  const float* tp_b2  = (const float*)d_in[16];
  const float* wih0   = (const float*)d_in[17];
  const float* whh0   = (const float*)d_in[18];
  const float* bih0   = (const float*)d_in[19];
  const float* bhh0   = (const float*)d_in[20];
  const float* wih1   = (const float*)d_in[21];
  const float* whh1   = (const float*)d_in[22];
  const float* bih1   = (const float*)d_in[23];
  const float* bhh1   = (const float*)d_in[24];
  const float* fg_w   = (const float*)d_in[25];
  const float* fg_b   = (const float*)d_in[26];
  const float* fs_w   = (const float*)d_in[27];
  const float* fs_b   = (const float*)d_in[28];
  const float* gate_w = (const float*)d_in[29];
  const float* gate_b = (const float*)d_in[30];
  const float* d1_w   = (const float*)d_in[31];
  const float* d1_b   = (const float*)d_in[32];
  const float* d2_w   = (const float*)d_in[33];
  const float* d2_b   = (const float*)d_in[34];
  float* ws = (float*)d_ws;
  float* outp = (float*)d_out;

  k_prep<<<1, 64, 0, stream>>>(eidx, ew, ws);
  k_wcfold<<<kGH + 1, kH, 0, stream>>>(post_w, post_b, fg_w, fg_b, ws);
  k_wq<<<768, 256, 0, stream>>>(whh0, whh1, ws);
  k_tpmlp<<<kBW / 16, 256, 0, stream>>>(r_seq, x_wls, tp_w1, tp_b1, tp_w2, tp_b2,
                                        ws + OFF_SPRE);
  k_gigemm<<<kBW / 16, 768, 0, stream>>>(ws + OFF_SPRE, wih0, bih0, ws + OFF_GI);
  k_scan<<<32, 512, 0, stream>>>(ws + OFF_GI, ws + OFF_WQ0, bhh0, ws + OFF_SPRE);
  k_gigemm<<<kBW / 16, 768, 0, stream>>>(ws + OFF_SPRE, wih1, bih1, ws + OFF_GI);
  k_scan<<<32, 512, 0, stream>>>(ws + OFF_GI, ws + OFF_WQ1, bhh1, ws + OFF_SPRE);
  // GI region is now dead -> bf16 B-fragment weights for k_fused
  k_wprep<<<(WB_TOT + 255) / 256, 256, 0, stream>>>(tag_w1, tag_w2, gate_w, d1_w, ws);
  k_fsgate<<<kBW / 16, 256, 0, stream>>>(ws + OFF_SPRE, fs_w, fs_b, gate_w, gate_b,
                                         ws + OFF_SFUSE, ws + OFF_SGATE);
  k_fused<<<kBW / 2, 512, 0, stream>>>(feat, x_wls, pre_w, pre_b, tag_b1, tag_b2,
                                       d1_b, d2_w, d2_b, ws, ws + OFF_SFUSE,
                                       ws + OFF_SGATE, outp);
}

// Round 11
// 1311.997 us; speedup vs baseline: 1.0601x; 1.0601x over previous
//
#include <hip/hip_runtime.h>
#include <hip/hip_fp16.h>
#include <cmath>

#define DEV __device__ __forceinline__

typedef unsigned short ushortT;
typedef short bs8 __attribute__((ext_vector_type(8)));
typedef float f32x4 __attribute__((ext_vector_type(4)));
typedef _Float16 f16x2 __attribute__((ext_vector_type(2)));

constexpr int kBW = 4096;          // B*W
constexpr int kM = 100, kF = 8, kN = 33, kH = 256, kGH = 128, kE = 64;

// ws offsets (in floats)
constexpr int OFF_ROWPTR  = 0;       // 34 int
constexpr int OFF_COLSRC  = 64;      // 64 int
constexpr int OFF_COLNORM = 128;     // 64 f
constexpr int OFF_C       = 192;     // 256 f (folded bias)
constexpr int OFF_WC      = 512;     // 128*256 f (post_w@fg_w)
constexpr int OFF_SPRE    = 33280;               // 4096*256 (s_pre -> s0 -> s1)
constexpr int OFF_GI      = OFF_SPRE + kBW * kH; // 4096*768 f
constexpr int OFF_SFUSE   = OFF_GI + kBW * 3 * kH;  // 4096*256 f
constexpr int OFF_SGATE   = OFF_SFUSE + kBW * kH;   // 4096*256 f
// scan weights (f16 pairs) live in SFUSE region (dead until k_fsgate):
constexpr int OFF_WQ0     = OFF_SFUSE;            // 98304 u32
constexpr int OFF_WQ1     = OFF_SFUSE + 98304;    // 98304 u32
// bf16 B-fragment weights for k_fused live in GI region (dead after scans):
constexpr int WB_TW1  = 0;        // 4*128*128
constexpr int WB_TW2  = 65536;    // 4*128*128
constexpr int WB_WC   = 131072;   // 256 cols x 128 k
constexpr int WB_GATE = 163840;   // 256 cols x 256 k
constexpr int WB_D1   = 229376;   // 256 cols x 256 k
constexpr int WB_TOT  = 294912;

DEV float frcp(float x) { return __builtin_amdgcn_rcpf(x); }
DEV float fsig(float x) { return frcp(1.0f + __expf(-x)); }
DEV float ftanh(float x) { float e = __expf(2.0f * x); return 1.0f - 2.0f * frcp(e + 1.0f); }

DEV ushortT f2bf(float x) {
  unsigned u = __float_as_uint(x);
  unsigned r = u + 0x7fffu + ((u >> 16) & 1u);
  return (ushortT)(r >> 16);
}
DEV float bf2f(ushortT u) { return __uint_as_float(((unsigned)u) << 16); }

DEV f32x4 mfma16(bs8 a, bs8 b, f32x4 c) {
  return __builtin_amdgcn_mfma_f32_16x16x32_bf16(a, b, c, 0, 0, 0);
}
DEV bs8 ldb(const ushortT* p) { return *reinterpret_cast<const bs8*>(p); }

#if __has_builtin(__builtin_amdgcn_fdot2)
DEV float dot2(unsigned w, unsigned hp, float acc) {
  f16x2 wv = __builtin_bit_cast(f16x2, w);
  f16x2 hv = __builtin_bit_cast(f16x2, hp);
  return __builtin_amdgcn_fdot2(wv, hv, acc, false);
}
#else
DEV float dot2(unsigned w, unsigned hp, float acc) {
  f16x2 wv = __builtin_bit_cast(f16x2, w);
  f16x2 hv = __builtin_bit_cast(f16x2, hp);
  acc = fmaf((float)wv.x, (float)hv.x, acc);
  acc = fmaf((float)wv.y, (float)hv.y, acc);
  return acc;
}
#endif

// ---------------- graph prep: degree norm + CSR by dst ---------------------------
__global__ void k_prep(const int* __restrict__ ei, const float* __restrict__ ew,
                       float* __restrict__ ws) {
  if (blockIdx.x != 0 || threadIdx.x != 0) return;
  int* rowptr = (int*)(ws + OFF_ROWPTR);
  int* colsrc = (int*)(ws + OFF_COLSRC);
  float* colnorm = ws + OFF_COLNORM;
  const int* src = ei;
  const int* dst = ei + kE;
  float deg[kN]; int cnt[kN];
  for (int n = 0; n < kN; ++n) { deg[n] = 0.f; cnt[n] = 0; }
  for (int e = 0; e < kE; ++e) { deg[dst[e]] += ew[e]; cnt[dst[e]]++; }
  float dinv[kN];
  for (int n = 0; n < kN; ++n) dinv[n] = deg[n] > 0.f ? 1.0f / sqrtf(deg[n]) : 0.f;
  int pos[kN];
  int run = 0;
  for (int n = 0; n < kN; ++n) { rowptr[n] = run; pos[n] = run; run += cnt[n]; }
  rowptr[kN] = run;
  for (int e = 0; e < kE; ++e) {
    int d = dst[e];
    int p = pos[d]++;
    colsrc[p] = src[e];
    colnorm[p] = dinv[src[e]] * ew[e] * dinv[d];
  }
}

// ---------------- fold Wc = post_w @ fg_w (128x256), c = post_b @ fg_w + fg_b -----
__global__ void k_wcfold(const float* __restrict__ post_w, const float* __restrict__ post_b,
                         const float* __restrict__ fg_w, const float* __restrict__ fg_b,
                         float* __restrict__ ws) {
  const int j = threadIdx.x;
  if ((int)blockIdx.x < kGH) {
    const int k = blockIdx.x;
    float a = 0.f;
    #pragma unroll 4
    for (int m = 0; m < kH; ++m) a = fmaf(post_w[k * kH + m], fg_w[m * kH + j], a);
    ws[OFF_WC + k * kH + j] = a;
  } else {
    float a = fg_b[j];
    #pragma unroll 4
    for (int m = 0; m < kH; ++m) a = fmaf(post_b[m], fg_w[m * kH + j], a);
    ws[OFF_C + j] = a;
  }
}

// ---------------- scan weights: whh[k][j] -> f16 pairs wq[(k/2)*768 + j] ----------
__global__ void k_wq(const float* __restrict__ w0, const float* __restrict__ w1,
                     float* __restrict__ ws) {
  const int idx = blockIdx.x * 256 + threadIdx.x;
  if (idx >= 2 * 98304) return;
  const int layer = idx / 98304;
  const int rem = idx - layer * 98304;
  const int p = rem / 768, j = rem - p * 768;
  const float* w = layer ? w1 : w0;
  unsigned* dst = (unsigned*)(ws + (layer ? OFF_WQ1 : OFF_WQ0));
  __half2 v = __floats2half2_rn(w[(2 * p) * 768 + j], w[(2 * p + 1) * 768 + j]);
  dst[rem] = *reinterpret_cast<unsigned*>(&v);
}

// ---------------- bf16 B-fragment weights ([col][k]) for k_fused -----------------
__global__ void k_wprep(const float* __restrict__ tw1, const float* __restrict__ tw2,
                        const float* __restrict__ gatew, const float* __restrict__ d1w,
                        float* __restrict__ ws) {
  const int idx = blockIdx.x * 256 + threadIdx.x;
  if (idx >= WB_TOT) return;
  ushortT* WB = (ushortT*)(ws + OFF_GI);
  float v; int dst;
  if (idx < 65536) {
    int s = idx >> 14, r = idx & 16383, k = r >> 7, col = r & 127;
    v = tw1[(s << 14) + (k << 7) + col]; dst = WB_TW1 + (s << 14) + (col << 7) + k;
  } else if (idx < 131072) {
    int i = idx - 65536; int s = i >> 14, r = i & 16383, k = r >> 7, col = r & 127;
    v = tw2[(s << 14) + (k << 7) + col]; dst = WB_TW2 + (s << 14) + (col << 7) + k;
  } else if (idx < 163840) {
    int i = idx - 131072; int k = i & 127, col = i >> 7;
    v = ws[OFF_WC + (k << 8) + col]; dst = WB_WC + (col << 7) + k;
  } else if (idx < 229376) {
    int i = idx - 163840; int k = i & 255, col = i >> 8;
    v = gatew[(k << 8) + col]; dst = WB_GATE + (col << 8) + k;
  } else {
    int i = idx - 229376; int k = i & 255, col = i >> 8;
    v = d1w[(k << 8) + col]; dst = WB_D1 + (col << 8) + k;
  }
  WB[dst] = f2bf(v);
}

// ---------------- temporal pre-MLP, 16 rows per block -----------------------------
__global__ __launch_bounds__(256) void k_tpmlp(
    const float* __restrict__ r_seq, const float* __restrict__ x_wls,
    const float* __restrict__ w1, const float* __restrict__ b1,
    const float* __restrict__ w2, const float* __restrict__ b2,
    float* __restrict__ sout) {
  __shared__ float inr[16][kM + 2 * kN];  // 16 x 166
  __shared__ float h1[16][kH];
  const int bw0 = blockIdx.x * 16, tid = threadIdx.x;
  #pragma unroll
  for (int r = 0; r < 16; ++r) {
    for (int c = tid; c < kM + 2 * kN; c += 256)
      inr[r][c] = (c < kM) ? r_seq[(bw0 + r) * kM + c]
                           : x_wls[(bw0 + r) * 2 * kN + (c - kM)];
  }
  __syncthreads();
  float acc[16];
  {
    const float bb = b1[tid];
    #pragma unroll
    for (int r = 0; r < 16; ++r) acc[r] = bb;
  }
  for (int k = 0; k < kM + 2 * kN; ++k) {
    const float w = w1[k * kH + tid];
    #pragma unroll
    for (int r = 0; r < 16; ++r) acc[r] = fmaf(inr[r][k], w, acc[r]);
  }
  #pragma unroll
  for (int r = 0; r < 16; ++r) h1[r][tid] = fmaxf(acc[r], 0.f);
  __syncthreads();
  {
    const float bb = b2[tid];
    #pragma unroll
    for (int r = 0; r < 16; ++r) acc[r] = bb;
  }
  #pragma unroll 2
  for (int k = 0; k < kH; ++k) {
    const float w = w2[k * kH + tid];
    #pragma unroll
    for (int r = 0; r < 16; ++r) acc[r] = fmaf(h1[r][k], w, acc[r]);
  }
  #pragma unroll
  for (int r = 0; r < 16; ++r) sout[(bw0 + r) * kH + tid] = fmaxf(acc[r], 0.f);
}

// ---------------- gi = s @ wih + bih, 16 rows per block ---------------------------
__global__ __launch_bounds__(768) void k_gigemm(
    const float* __restrict__ sin, const float* __restrict__ wih,
    const float* __restrict__ bih, float* __restrict__ gi) {
  __shared__ float sr[16][kH];
  const int bw0 = blockIdx.x * 16, tid = threadIdx.x;
  for (int i = tid; i < 16 * kH; i += 768) sr[i >> 8][i & 255] = sin[bw0 * kH + i];
  __syncthreads();
  float acc[16];
  {
    const float bb = bih[tid];
    #pragma unroll
    for (int r = 0; r < 16; ++r) acc[r] = bb;
  }
  #pragma unroll 2
  for (int k = 0; k < kH; ++k) {
    const float w = wih[k * 768 + tid];
    #pragma unroll
    for (int r = 0; r < 16; ++r) acc[r] = fmaf(sr[r][k], w, acc[r]);
  }
  #pragma unroll
  for (int r = 0; r < 16; ++r) gi[(bw0 + r) * 768 + tid] = acc[r];
}

// ---------------- GRU scan: pair-split columns, weights in VGPRs (R9, kept) -------
__global__ __launch_bounds__(512, 2) void k_scan(
    const float* __restrict__ gi, const float* __restrict__ wq,
    const float* __restrict__ bhh, float* __restrict__ sout) {
  __shared__ __align__(16) unsigned hpk[2][kH / 2];
  const int b = blockIdx.x, tid = threadIdx.x;
  const int c = tid >> 1, hh = tid & 1;
  const unsigned* wqp = (const unsigned*)wq + hh * 64 * 768 + c;
  unsigned wA[64], wB[64], wC[64];
  #pragma unroll
  for (int p = 0; p < 64; ++p) {
    wA[p] = wqp[p * 768];
    wB[p] = wqp[p * 768 + 256];
    wC[p] = wqp[p * 768 + 512];
  }
  const float bR = bhh[c], bZ = bhh[kH + c], bN = bhh[2 * kH + c];
  if (tid < kH / 2) hpk[0][tid] = 0u;
  float h = 0.f;
  __syncthreads();
  const float* gbase = gi + b * 128 * 768 + c;
  for (int t = 0; t < 128; ++t) {
    const float* g = gbase + t * 768;
    const float gA = g[0], gB = g[256], gC = g[512];
    float aR0 = 0.f, aR1 = 0.f, aZ0 = 0.f, aZ1 = 0.f, aN0 = 0.f, aN1 = 0.f;
    const unsigned* hb = hpk[t & 1] + hh * 64;
    #pragma unroll
    for (int q = 0; q < 16; ++q) {
      const uint4 hp = *reinterpret_cast<const uint4*>(hb + 4 * q);
      aR0 = dot2(wA[4 * q + 0], hp.x, aR0);
      aZ0 = dot2(wB[4 * q + 0], hp.x, aZ0);
      aN0 = dot2(wC[4 * q + 0], hp.x, aN0);
      aR1 = dot2(wA[4 * q + 1], hp.y, aR1);
      aZ1 = dot2(wB[4 * q + 1], hp.y, aZ1);
      aN1 = dot2(wC[4 * q + 1], hp.y, aN1);
      aR0 = dot2(wA[4 * q + 2], hp.z, aR0);
      aZ0 = dot2(wB[4 * q + 2], hp.z, aZ0);
      aN0 = dot2(wC[4 * q + 2], hp.z, aN0);
      aR1 = dot2(wA[4 * q + 3], hp.w, aR1);
      aZ1 = dot2(wB[4 * q + 3], hp.w, aZ1);
      aN1 = dot2(wC[4 * q + 3], hp.w, aN1);
    }
    float aR = aR0 + aR1; aR += __shfl_xor(aR, 1, 64);
    float aZ = aZ0 + aZ1; aZ += __shfl_xor(aZ, 1, 64);
    float aN = aN0 + aN1; aN += __shfl_xor(aN, 1, 64);
    const float r = fsig(gA + bR + aR);
    const float z = fsig(gB + bZ + aZ);
    const float n = ftanh(fmaf(r, aN + bN, gC));
    h = (1.f - z) * n + z * h;
    if (hh == 0) reinterpret_cast<__half*>(hpk[(t + 1) & 1])[c] = __float2half(h);
    else sout[(b * 128 + t) * kH + c] = h;
    __syncthreads();
  }
}

// ---------------- sfuse/sgate, 16 rows per block ----------------------------------
__global__ __launch_bounds__(256) void k_fsgate(
    const float* __restrict__ s1, const float* __restrict__ fsw,
    const float* __restrict__ fsb, const float* __restrict__ gw,
    const float* __restrict__ gb, float* __restrict__ sfuse,
    float* __restrict__ sgate) {
  __shared__ float sr[16][kH], sf[16][kH];
  const int bw0 = blockIdx.x * 16, tid = threadIdx.x;
  for (int i = tid; i < 16 * kH; i += 256) sr[i >> 8][i & 255] = s1[bw0 * kH + i];
  __syncthreads();
  float acc[16];
  {
    const float bb = fsb[tid];
    #pragma unroll
    for (int r = 0; r < 16; ++r) acc[r] = bb;
  }
  #pragma unroll 2
  for (int k = 0; k < kH; ++k) {
    const float w = fsw[k * kH + tid];
    #pragma unroll
    for (int r = 0; r < 16; ++r) acc[r] = fmaf(sr[r][k], w, acc[r]);
  }
  #pragma unroll
  for (int r = 0; r < 16; ++r) { sf[r][tid] = acc[r]; sfuse[(bw0 + r) * kH + tid] = acc[r]; }
  __syncthreads();
  {
    const float bb = gb[tid];
    #pragma unroll
    for (int r = 0; r < 16; ++r) acc[r] = bb;
  }
  #pragma unroll 2
  for (int k = 0; k < kH; ++k) {
    const float w = gw[(kH + k) * kH + tid];
    #pragma unroll
    for (int r = 0; r < 16; ++r) acc[r] = fmaf(sf[r][k], w, acc[r]);
  }
  #pragma unroll
  for (int r = 0; r < 16; ++r) sgate[(bw0 + r) * kH + tid] = acc[r];
}

// ================= fused GNN + gate + decoder (MFMA bf16, 8 waves) ================
// R9 structure (1 graph/block, 512 threads, grid 4096) + R10's PROVEN stride fix:
// buf stride 132 ushorts (66 dwords == 2 mod 32), GT stride 260 (130 dwords ==
// 2 mod 32). Adjacent 16-lane reads land on distinct bank pairs; worst 2-way
// aliasing is free (m136). R9's 136/264 (== 4 mod 32) cost 19.4M conflict
// cycles/dispatch (~9%). R10's 2-graph fusion is REVERTED (halved occupancy,
// doubled phase latency: 367 -> 785 us).

constexpr int BSTR = 132;               // buf row stride (ushorts)
constexpr int GSTR = 260;               // GT row stride (ushorts)
constexpr int SB0 = 0;
constexpr int SB1 = 36 * BSTR;          // 4752
constexpr int S_TOT = 2 * 36 * BSTR;    // 9504 ushorts = 19008 B (GT 36x260=9360 fits)

// dst(rows<33) = P @ src, bf16 pairs (512-thread grid-stride; 66 pairs/row)
DEV void propb(ushortT* __restrict__ dst, const ushortT* __restrict__ src,
               const int* __restrict__ rp, const int* __restrict__ cs,
               const float* __restrict__ cn) {
  for (int idx = threadIdx.x; idx < kN * 66; idx += 512) {
    const int n = idx / 66, j2 = idx - n * 66;
    float a0 = 0.f, a1 = 0.f;
    const int p1 = rp[n + 1];
    for (int p = rp[n]; p < p1; ++p) {
      const unsigned v = *(const unsigned*)(src + cs[p] * BSTR + 2 * j2);
      const float w = cn[p];
      a0 = fmaf(__uint_as_float(v << 16), w, a0);
      a1 = fmaf(__uint_as_float(v & 0xffff0000u), w, a1);
    }
    *(unsigned*)(dst + n * BSTR + 2 * j2) = (unsigned)f2bf(a0) | ((unsigned)f2bf(a1) << 16);
  }
}

// tag pass: buf0(h) -> buf0(out), ping-pong with buf1. W stacked 4x[col][k].
template <bool RELU>
DEV void tag_mfma(ushortT* __restrict__ Sb, const ushortT* __restrict__ WT,
                  const float* __restrict__ b, const int* __restrict__ rp,
                  const int* __restrict__ cs, const float* __restrict__ cn,
                  int wv, int lane) {
  const int lr = lane & 15, lg = lane >> 4;
  const int col = wv * 16 + lr;
  f32x4 acc[3];
  #pragma unroll
  for (int i = 0; i < 3; ++i) acc[i] = (f32x4){0.f, 0.f, 0.f, 0.f};
  #pragma unroll
  for (int s = 0; s < 4; ++s) {
    const ushortT* A = Sb + ((s & 1) ? SB1 : SB0);
    ushortT* Bn      = Sb + ((s & 1) ? SB0 : SB1);
    #pragma unroll
    for (int ks = 0; ks < 4; ++ks) {
      const int kof = ks * 32 + lg * 8;
      bs8 a0 = ldb(A + (lr) * BSTR + kof);
      bs8 a1 = ldb(A + (16 + lr) * BSTR + kof);
      bs8 a2 = ldb(A + (32 + lr) * BSTR + kof);
      bs8 bb = ldb(WT + (s << 14) + (col << 7) + kof);
      acc[0] = mfma16(a0, bb, acc[0]);
      acc[1] = mfma16(a1, bb, acc[1]);
      acc[2] = mfma16(a2, bb, acc[2]);
    }
    if (s < 3) {
      propb(Bn, A, rp, cs, cn);
      __syncthreads();
    }
  }
  __syncthreads();  // all s=3 A-reads complete before overwriting buf0
  const float bias = b[col];
  #pragma unroll
  for (int mt = 0; mt < 3; ++mt)
    #pragma unroll
    for (int r = 0; r < 4; ++r) {
      const int row = mt * 16 + lg * 4 + r;
      if (row < kN) {
        float x = acc[mt][r] + bias;
        if (RELU) x = fmaxf(x, 0.f);
        (Sb + SB0)[row * BSTR + col] = f2bf(x);
      }
    }
  __syncthreads();
}

__global__ __launch_bounds__(512, 4) void k_fused(
    const float* __restrict__ feat_seq, const float* __restrict__ x_wls,
    const float* __restrict__ pre_w, const float* __restrict__ pre_b,
    const float* __restrict__ tb1, const float* __restrict__ tb2,
    const float* __restrict__ d1b, const float* __restrict__ d2w,
    const float* __restrict__ d2b, const float* __restrict__ ws,
    const float* __restrict__ sfuse, const float* __restrict__ sgate,
    float* __restrict__ out) {
  __shared__ __align__(16) ushortT S[S_TOT];
  __shared__ float sfrow[kH], sgrow[kH];
  __shared__ float xw[2 * kN];
  __shared__ float featl[kF];
  __shared__ int rp[kN + 1], cs[kE];
  __shared__ float cn[kE];
  __shared__ float part[8][48][2];
  const int tid = threadIdx.x, bw = blockIdx.x;
  const int wv = tid >> 6, lane = tid & 63;
  const int lr = lane & 15, lg = lane >> 4;
  const ushortT* WB = (const ushortT*)(ws + OFF_GI);
  ushortT* GT = S;  // 36 rows x 260, overlaps buf0+buf1

  if (tid < kH) sfrow[tid] = sfuse[bw * kH + tid];
  else if (tid < 2 * kH) sgrow[tid - kH] = sgate[bw * kH + (tid - kH)];
  if (tid < 2 * kN) xw[tid] = x_wls[bw * 2 * kN + tid];
  else if (tid >= 66 && tid < 66 + kF) featl[tid - 66] = feat_seq[bw * kF + (tid - 66)];
  if (tid >= 128 && tid < 128 + kN + 1) rp[tid - 128] = ((const int*)(ws + OFF_ROWPTR))[tid - 128];
  if (tid >= 192 && tid < 256) {
    cs[tid - 192] = ((const int*)(ws + OFF_COLSRC))[tid - 192];
    cn[tid - 192] = ws[OFF_COLNORM + (tid - 192)];
  }
  // zero pad rows 33..35 of buf0 and buf1 (full BSTR-col rows)
  if (tid < 3 * BSTR) {
    S[SB0 + kN * BSTR + tid] = 0;
    S[SB1 + kN * BSTR + tid] = 0;
  }
  __syncthreads();

  // gin = [feat(8), va, vm] @ pre_w + pre_b  -> buf0 (33x128 bf16)
  for (int idx = tid; idx < kN * kGH; idx += 512) {
    const int n = idx >> 7, j = idx & 127;
    float a = pre_b[j];
    #pragma unroll
    for (int f = 0; f < kF; ++f) a = fmaf(featl[f], pre_w[f * kGH + j], a);
    a = fmaf(xw[n], pre_w[8 * kGH + j], a);
    a = fmaf(xw[kN + n], pre_w[9 * kGH + j], a);
    S[SB0 + n * BSTR + j] = f2bf(a);
  }
  __syncthreads();

  tag_mfma<true >(S, WB + WB_TW1, tb1, rp, cs, cn, wv, lane);
  tag_mfma<false>(S, WB + WB_TW2, tb2, rp, cs, cn, wv, lane);

  // ---- g_t = G @ Wc + c -> GT (33x256 bf16), regs then overwrite ----
  {
    f32x4 acc[6];
    #pragma unroll
    for (int i = 0; i < 6; ++i) acc[i] = (f32x4){0.f, 0.f, 0.f, 0.f};
    #pragma unroll
    for (int ks = 0; ks < 4; ++ks) {
      const int kof = ks * 32 + lg * 8;
      bs8 a0 = ldb(S + SB0 + (lr) * BSTR + kof);
      bs8 a1 = ldb(S + SB0 + (16 + lr) * BSTR + kof);
      bs8 a2 = ldb(S + SB0 + (32 + lr) * BSTR + kof);
      #pragma unroll
      for (int nt = 0; nt < 2; ++nt) {
        const int col = (wv * 2 + nt) * 16 + lr;
        bs8 bb = ldb(WB + WB_WC + (col << 7) + kof);
        acc[0 + nt] = mfma16(a0, bb, acc[0 + nt]);
        acc[2 + nt] = mfma16(a1, bb, acc[2 + nt]);
        acc[4 + nt] = mfma16(a2, bb, acc[4 + nt]);
      }
    }
    __syncthreads();  // all buf reads done; S becomes GT
    #pragma unroll
    for (int mt = 0; mt < 3; ++mt)
      #pragma unroll
      for (int nt = 0; nt < 2; ++nt) {
        const int col = (wv * 2 + nt) * 16 + lr;
        const float cb = ws[OFF_C + col];
        const f32x4 v = acc[mt * 2 + nt];
        #pragma unroll
        for (int r = 0; r < 4; ++r) {
          const int row = mt * 16 + lg * 4 + r;
          if (row < kN) GT[row * GSTR + col] = f2bf(v[r] + cb);
        }
      }
    __syncthreads();
  }

  // ---- gate: alpha = sigmoid(GT @ gate_w + sgate); U = a*gt + (1-a)*sfuse -> GT --
  {
    f32x4 acc[6];
    #pragma unroll
    for (int i = 0; i < 6; ++i) acc[i] = (f32x4){0.f, 0.f, 0.f, 0.f};
    #pragma unroll 2
    for (int ks = 0; ks < 8; ++ks) {
      const int kof = ks * 32 + lg * 8;
      const int r2 = (32 + lr) < 36 ? (32 + lr) : 35;  // clamp: GT has 36 rows
      bs8 a0 = ldb(GT + (lr) * GSTR + kof);
      bs8 a1 = ldb(GT + (16 + lr) * GSTR + kof);
      bs8 a2 = ldb(GT + r2 * GSTR + kof);
      #pragma unroll
      for (int nt = 0; nt < 2; ++nt) {
        const int col = (wv * 2 + nt) * 16 + lr;
        bs8 bb = ldb(WB + WB_GATE + (col << 8) + kof);
        acc[0 + nt] = mfma16(a0, bb, acc[0 + nt]);
        acc[2 + nt] = mfma16(a1, bb, acc[2 + nt]);
        acc[4 + nt] = mfma16(a2, bb, acc[4 + nt]);
      }
    }
    // compute U into acc (reads GT), then barrier, then write U over GT
    #pragma unroll
    for (int mt = 0; mt < 3; ++mt)
      #pragma unroll
      for (int nt = 0; nt < 2; ++nt) {
        const int col = (wv * 2 + nt) * 16 + lr;
        const float sg = sgrow[col], sf = sfrow[col];
        #pragma unroll
        for (int r = 0; r < 4; ++r) {
          const int row = mt * 16 + lg * 4 + r;
          if (row < kN) {
            const float al = fsig(acc[mt * 2 + nt][r] + sg);
            const float gt = bf2f(GT[row * GSTR + col]);
            acc[mt * 2 + nt][r] = al * gt + (1.f - al) * sf;
          }
        }
      }
    __syncthreads();
    #pragma unroll
    for (int mt = 0; mt < 3; ++mt)
      #pragma unroll
      for (int nt = 0; nt < 2; ++nt) {
        const int col = (wv * 2 + nt) * 16 + lr;
        #pragma unroll
        for (int r = 0; r < 4; ++r) {
          const int row = mt * 16 + lg * 4 + r;
          if (row < kN) GT[row * GSTR + col] = f2bf(acc[mt * 2 + nt][r]);
        }
      }
    __syncthreads();
  }

  // ---- d1: V = relu(U @ d1w + d1b); d2 (256->2) + residual ----
  {
    f32x4 acc[6];
    #pragma unroll
    for (int i = 0; i < 6; ++i) acc[i] = (f32x4){0.f, 0.f, 0.f, 0.f};
    #pragma unroll 2
    for (int ks = 0; ks < 8; ++ks) {
      const int kof = ks * 32 + lg * 8;
      const int r2 = (32 + lr) < 36 ? (32 + lr) : 35;
      bs8 a0 = ldb(GT + (lr) * GSTR + kof);
      bs8 a1 = ldb(GT + (16 + lr) * GSTR + kof);
      bs8 a2 = ldb(GT + r2 * GSTR + kof);
      #pragma unroll
      for (int nt = 0; nt < 2; ++nt) {
        const int col = (wv * 2 + nt) * 16 + lr;
        bs8 bb = ldb(WB + WB_D1 + (col << 8) + kof);
        acc[0 + nt] = mfma16(a0, bb, acc[0 + nt]);
        acc[2 + nt] = mfma16(a1, bb, acc[2 + nt]);
        acc[4 + nt] = mfma16(a2, bb, acc[4 + nt]);
      }
    }
    float p0[3][4], p1[3][4];
    #pragma unroll
    for (int mt = 0; mt < 3; ++mt)
      #pragma unroll
      for (int r = 0; r < 4; ++r) { p0[mt][r] = 0.f; p1[mt][r] = 0.f; }
    #pragma unroll
    for (int nt = 0; nt < 2; ++nt) {
      const int col = (wv * 2 + nt) * 16 + lr;
      const float db = d1b[col];
      const float2 dp = *reinterpret_cast<const float2*>(d2w + col * 2);
      #pragma unroll
      for (int mt = 0; mt < 3; ++mt)
        #pragma unroll
        for (int r = 0; r < 4; ++r) {
          const float v = fmaxf(acc[mt * 2 + nt][r] + db, 0.f);
          p0[mt][r] = fmaf(v, dp.x, p0[mt][r]);
          p1[mt][r] = fmaf(v, dp.y, p1[mt][r]);
        }
    }
    #pragma unroll
    for (int mt = 0; mt < 3; ++mt)
      #pragma unroll
      for (int r = 0; r < 4; ++r) {
        #pragma unroll
        for (int off = 1; off < 16; off <<= 1) {
          p0[mt][r] += __shfl_xor(p0[mt][r], off, 64);
          p1[mt][r] += __shfl_xor(p1[mt][r], off, 64);
        }
      }
    if (lr == 0) {
      #pragma unroll
      for (int mt = 0; mt < 3; ++mt)
        #pragma unroll
        for (int r = 0; r < 4; ++r) {
          const int row = mt * 16 + lg * 4 + r;
          part[wv][row][0] = p0[mt][r];
          part[wv][row][1] = p1[mt][r];
        }
    }
    __syncthreads();
    if (tid < 66) {
      const int c = tid >= 33 ? 1 : 0;
      const int n = tid - 33 * c;
      float s = d2b[c];
      #pragma unroll
      for (int w = 0; w < 8; ++w) s += part[w][n][c];
      out[bw * 66 + tid] = xw[tid] + s;
    }
  }
}

extern "C" void kernel_launch(void* const* d_in, const int* in_sizes, int n_in,
                              void* d_out, int out_size, void* d_ws, size_t ws_size,
                              hipStream_t stream) {
  const float* r_seq  = (const float*)d_in[0];
  const float* feat   = (const float*)d_in[1];
  const float* x_wls  = (const float*)d_in[2];
  const int*   eidx   = (const int*)d_in[3];
  const float* ew     = (const float*)d_in[4];
  const float* pre_w  = (const float*)d_in[5];
  const float* pre_b  = (const float*)d_in[6];
  const float* tag_w1 = (const float*)d_in[7];
  const float* tag_b1 = (const float*)d_in[8];
  const float* tag_w2 = (const float*)d_in[9];
  const float* tag_b2 = (const float*)d_in[10];
  const float* post_w = (const float*)d_in[11];
  const float* post_b = (const float*)d_in[12];
  const float* tp_w1  = (const float*)d_in[13];
  const float* tp_b1  = (const float*)d_in[14];
  const float* tp_w2  = (const float*)d_in[15];
  const float* tp_b2  = (const float*)d_in[16];
  const float* wih0   = (const float*)d_in[17];
  const float* whh0   = (const float*)d_in[18];
  const float* bih0   = (const float*)d_in[19];
  const float* bhh0   = (const float*)d_in[20];
  const float* wih1   = (const float*)d_in[21];
  const float* whh1   = (const float*)d_in[22];
  const float* bih1   = (const float*)d_in[23];
  const float* bhh1   = (const float*)d_in[24];
  const float* fg_w   = (const float*)d_in[25];
  const float* fg_b   = (const float*)d_in[26];
  const float* fs_w   = (const float*)d_in[27];
  const float* fs_b   = (const float*)d_in[28];
  const float* gate_w = (const float*)d_in[29];
  const float* gate_b = (const float*)d_in[30];
  const float* d1_w   = (const float*)d_in[31];
  const float* d1_b   = (const float*)d_in[32];
  const float* d2_w   = (const float*)d_in[33];
  const float* d2_b   = (const float*)d_in[34];
  float* ws = (float*)d_ws;
  float* outp = (float*)d_out;

  k_prep<<<1, 64, 0, stream>>>(eidx, ew, ws);
  k_wcfold<<<kGH + 1, kH, 0, stream>>>(post_w, post_b, fg_w, fg_b, ws);
  k_wq<<<768, 256, 0, stream>>>(whh0, whh1, ws);
  k_tpmlp<<<kBW / 16, 256, 0, stream>>>(r_seq, x_wls, tp_w1, tp_b1, tp_w2, tp_b2,
                                        ws + OFF_SPRE);
  k_gigemm<<<kBW / 16, 768, 0, stream>>>(ws + OFF_SPRE, wih0, bih0, ws + OFF_GI);
  k_scan<<<32, 512, 0, stream>>>(ws + OFF_GI, ws + OFF_WQ0, bhh0, ws + OFF_SPRE);
  k_gigemm<<<kBW / 16, 768, 0, stream>>>(ws + OFF_SPRE, wih1, bih1, ws + OFF_GI);
  k_scan<<<32, 512, 0, stream>>>(ws + OFF_GI, ws + OFF_WQ1, bhh1, ws + OFF_SPRE);
  // GI region is now dead -> bf16 B-fragment weights for k_fused
  k_wprep<<<(WB_TOT + 255) / 256, 256, 0, stream>>>(tag_w1, tag_w2, gate_w, d1_w, ws);
  k_fsgate<<<kBW / 16, 256, 0, stream>>>(ws + OFF_SPRE, fs_w, fs_b, gate_w, gate_b,
                                         ws + OFF_SFUSE, ws + OFF_SGATE);
  k_fused<<<kBW, 512, 0, stream>>>(feat, x_wls, pre_w, pre_b, tag_b1, tag_b2,
                                   d1_b, d2_w, d2_b, ws, ws + OFF_SFUSE,
                                   ws + OFF_SGATE, outp);
}

// Round 12
// 978.050 us; speedup vs baseline: 1.4221x; 1.3414x over previous
//
#include <hip/hip_runtime.h>
#include <hip/hip_fp16.h>
#include <cmath>

#define DEV __device__ __forceinline__

typedef unsigned short ushortT;
typedef short bs8 __attribute__((ext_vector_type(8)));
typedef float f32x4 __attribute__((ext_vector_type(4)));
typedef _Float16 f16x2 __attribute__((ext_vector_type(2)));

constexpr int kBW = 4096;          // B*W
constexpr int kM = 100, kF = 8, kN = 33, kH = 256, kGH = 128, kE = 64;

// ws offsets (in floats)
constexpr int OFF_ROWPTR  = 0;       // 34 int
constexpr int OFF_COLSRC  = 64;      // 64 int
constexpr int OFF_COLNORM = 128;     // 64 f
constexpr int OFF_C       = 192;     // 256 f (folded bias)
constexpr int OFF_WC      = 512;     // 128*256 f (post_w@fg_w)
constexpr int OFF_SPRE    = 33280;               // 4096*256 (s_pre -> s0 -> s1)
constexpr int OFF_GI      = OFF_SPRE + kBW * kH; // 4096*768 f
constexpr int OFF_SFUSE   = OFF_GI + kBW * 3 * kH;  // 4096*256 f
constexpr int OFF_SGATE   = OFF_SFUSE + kBW * kH;   // 4096*256 f
// scan weights (f16 pairs) live in SFUSE region (dead until k_fsgate):
constexpr int OFF_WQ0     = OFF_SFUSE;            // 98304 u32
constexpr int OFF_WQ1     = OFF_SFUSE + 98304;    // 98304 u32
// bf16 B-fragment weights for k_fused live in GI region (dead after scans):
constexpr int WB_TW1  = 0;        // 4*128*128
constexpr int WB_TW2  = 65536;    // 4*128*128
constexpr int WB_WC   = 131072;   // 256 cols x 128 k
constexpr int WB_GATE = 163840;   // 256 cols x 256 k
constexpr int WB_D1   = 229376;   // 256 cols x 256 k
constexpr int WB_TOT  = 294912;

DEV float frcp(float x) { return __builtin_amdgcn_rcpf(x); }
DEV float fsig(float x) { return frcp(1.0f + __expf(-x)); }
DEV float ftanh(float x) { float e = __expf(2.0f * x); return 1.0f - 2.0f * frcp(e + 1.0f); }

DEV ushortT f2bf(float x) {
  unsigned u = __float_as_uint(x);
  unsigned r = u + 0x7fffu + ((u >> 16) & 1u);
  return (ushortT)(r >> 16);
}
DEV float bf2f(ushortT u) { return __uint_as_float(((unsigned)u) << 16); }

DEV f32x4 mfma16(bs8 a, bs8 b, f32x4 c) {
  return __builtin_amdgcn_mfma_f32_16x16x32_bf16(a, b, c, 0, 0, 0);
}
DEV bs8 ldb(const ushortT* p) { return *reinterpret_cast<const bs8*>(p); }

#if __has_builtin(__builtin_amdgcn_fdot2)
DEV float dot2(unsigned w, unsigned hp, float acc) {
  f16x2 wv = __builtin_bit_cast(f16x2, w);
  f16x2 hv = __builtin_bit_cast(f16x2, hp);
  return __builtin_amdgcn_fdot2(wv, hv, acc, false);
}
#else
DEV float dot2(unsigned w, unsigned hp, float acc) {
  f16x2 wv = __builtin_bit_cast(f16x2, w);
  f16x2 hv = __builtin_bit_cast(f16x2, hp);
  acc = fmaf((float)wv.x, (float)hv.x, acc);
  acc = fmaf((float)wv.y, (float)hv.y, acc);
  return acc;
}
#endif

// ---------------- graph prep: degree norm + CSR by dst ---------------------------
__global__ void k_prep(const int* __restrict__ ei, const float* __restrict__ ew,
                       float* __restrict__ ws) {
  if (blockIdx.x != 0 || threadIdx.x != 0) return;
  int* rowptr = (int*)(ws + OFF_ROWPTR);
  int* colsrc = (int*)(ws + OFF_COLSRC);
  float* colnorm = ws + OFF_COLNORM;
  const int* src = ei;
  const int* dst = ei + kE;
  float deg[kN]; int cnt[kN];
  for (int n = 0; n < kN; ++n) { deg[n] = 0.f; cnt[n] = 0; }
  for (int e = 0; e < kE; ++e) { deg[dst[e]] += ew[e]; cnt[dst[e]]++; }
  float dinv[kN];
  for (int n = 0; n < kN; ++n) dinv[n] = deg[n] > 0.f ? 1.0f / sqrtf(deg[n]) : 0.f;
  int pos[kN];
  int run = 0;
  for (int n = 0; n < kN; ++n) { rowptr[n] = run; pos[n] = run; run += cnt[n]; }
  rowptr[kN] = run;
  for (int e = 0; e < kE; ++e) {
    int d = dst[e];
    int p = pos[d]++;
    colsrc[p] = src[e];
    colnorm[p] = dinv[src[e]] * ew[e] * dinv[d];
  }
}

// ---------------- fold Wc = post_w @ fg_w (128x256), c = post_b @ fg_w + fg_b -----
__global__ void k_wcfold(const float* __restrict__ post_w, const float* __restrict__ post_b,
                         const float* __restrict__ fg_w, const float* __restrict__ fg_b,
                         float* __restrict__ ws) {
  const int j = threadIdx.x;
  if ((int)blockIdx.x < kGH) {
    const int k = blockIdx.x;
    float a = 0.f;
    #pragma unroll 4
    for (int m = 0; m < kH; ++m) a = fmaf(post_w[k * kH + m], fg_w[m * kH + j], a);
    ws[OFF_WC + k * kH + j] = a;
  } else {
    float a = fg_b[j];
    #pragma unroll 4
    for (int m = 0; m < kH; ++m) a = fmaf(post_b[m], fg_w[m * kH + j], a);
    ws[OFF_C + j] = a;
  }
}

// ---------------- scan weights: whh[k][j] -> f16 pairs wq[(k/2)*768 + j] ----------
__global__ void k_wq(const float* __restrict__ w0, const float* __restrict__ w1,
                     float* __restrict__ ws) {
  const int idx = blockIdx.x * 256 + threadIdx.x;
  if (idx >= 2 * 98304) return;
  const int layer = idx / 98304;
  const int rem = idx - layer * 98304;
  const int p = rem / 768, j = rem - p * 768;
  const float* w = layer ? w1 : w0;
  unsigned* dst = (unsigned*)(ws + (layer ? OFF_WQ1 : OFF_WQ0));
  __half2 v = __floats2half2_rn(w[(2 * p) * 768 + j], w[(2 * p + 1) * 768 + j]);
  dst[rem] = *reinterpret_cast<unsigned*>(&v);
}

// ---------------- bf16 B-fragment weights ([col][k]) for k_fused -----------------
__global__ void k_wprep(const float* __restrict__ tw1, const float* __restrict__ tw2,
                        const float* __restrict__ gatew, const float* __restrict__ d1w,
                        float* __restrict__ ws) {
  const int idx = blockIdx.x * 256 + threadIdx.x;
  if (idx >= WB_TOT) return;
  ushortT* WB = (ushortT*)(ws + OFF_GI);
  float v; int dst;
  if (idx < 65536) {
    int s = idx >> 14, r = idx & 16383, k = r >> 7, col = r & 127;
    v = tw1[(s << 14) + (k << 7) + col]; dst = WB_TW1 + (s << 14) + (col << 7) + k;
  } else if (idx < 131072) {
    int i = idx - 65536; int s = i >> 14, r = i & 16383, k = r >> 7, col = r & 127;
    v = tw2[(s << 14) + (k << 7) + col]; dst = WB_TW2 + (s << 14) + (col << 7) + k;
  } else if (idx < 163840) {
    int i = idx - 131072; int k = i & 127, col = i >> 7;
    v = ws[OFF_WC + (k << 8) + col]; dst = WB_WC + (col << 7) + k;
  } else if (idx < 229376) {
    int i = idx - 163840; int k = i & 255, col = i >> 8;
    v = gatew[(k << 8) + col]; dst = WB_GATE + (col << 8) + k;
  } else {
    int i = idx - 229376; int k = i & 255, col = i >> 8;
    v = d1w[(k << 8) + col]; dst = WB_D1 + (col << 8) + k;
  }
  WB[dst] = f2bf(v);
}

// ---------------- temporal pre-MLP, 16 rows per block -----------------------------
__global__ __launch_bounds__(256) void k_tpmlp(
    const float* __restrict__ r_seq, const float* __restrict__ x_wls,
    const float* __restrict__ w1, const float* __restrict__ b1,
    const float* __restrict__ w2, const float* __restrict__ b2,
    float* __restrict__ sout) {
  __shared__ float inr[16][kM + 2 * kN];  // 16 x 166
  __shared__ float h1[16][kH];
  const int bw0 = blockIdx.x * 16, tid = threadIdx.x;
  #pragma unroll
  for (int r = 0; r < 16; ++r) {
    for (int c = tid; c < kM + 2 * kN; c += 256)
      inr[r][c] = (c < kM) ? r_seq[(bw0 + r) * kM + c]
                           : x_wls[(bw0 + r) * 2 * kN + (c - kM)];
  }
  __syncthreads();
  float acc[16];
  {
    const float bb = b1[tid];
    #pragma unroll
    for (int r = 0; r < 16; ++r) acc[r] = bb;
  }
  for (int k = 0; k < kM + 2 * kN; ++k) {
    const float w = w1[k * kH + tid];
    #pragma unroll
    for (int r = 0; r < 16; ++r) acc[r] = fmaf(inr[r][k], w, acc[r]);
  }
  #pragma unroll
  for (int r = 0; r < 16; ++r) h1[r][tid] = fmaxf(acc[r], 0.f);
  __syncthreads();
  {
    const float bb = b2[tid];
    #pragma unroll
    for (int r = 0; r < 16; ++r) acc[r] = bb;
  }
  #pragma unroll 2
  for (int k = 0; k < kH; ++k) {
    const float w = w2[k * kH + tid];
    #pragma unroll
    for (int r = 0; r < 16; ++r) acc[r] = fmaf(h1[r][k], w, acc[r]);
  }
  #pragma unroll
  for (int r = 0; r < 16; ++r) sout[(bw0 + r) * kH + tid] = fmaxf(acc[r], 0.f);
}

// ---------------- gi = s @ wih + bih, 16 rows per block ---------------------------
__global__ __launch_bounds__(768) void k_gigemm(
    const float* __restrict__ sin, const float* __restrict__ wih,
    const float* __restrict__ bih, float* __restrict__ gi) {
  __shared__ float sr[16][kH];
  const int bw0 = blockIdx.x * 16, tid = threadIdx.x;
  for (int i = tid; i < 16 * kH; i += 768) sr[i >> 8][i & 255] = sin[bw0 * kH + i];
  __syncthreads();
  float acc[16];
  {
    const float bb = bih[tid];
    #pragma unroll
    for (int r = 0; r < 16; ++r) acc[r] = bb;
  }
  #pragma unroll 2
  for (int k = 0; k < kH; ++k) {
    const float w = wih[k * 768 + tid];
    #pragma unroll
    for (int r = 0; r < 16; ++r) acc[r] = fmaf(sr[r][k], w, acc[r]);
  }
  #pragma unroll
  for (int r = 0; r < 16; ++r) gi[(bw0 + r) * 768 + tid] = acc[r];
}

// ---------------- GRU scan: pair-split columns, weights in VGPRs (R9, kept) -------
__global__ __launch_bounds__(512, 2) void k_scan(
    const float* __restrict__ gi, const float* __restrict__ wq,
    const float* __restrict__ bhh, float* __restrict__ sout) {
  __shared__ __align__(16) unsigned hpk[2][kH / 2];
  const int b = blockIdx.x, tid = threadIdx.x;
  const int c = tid >> 1, hh = tid & 1;
  const unsigned* wqp = (const unsigned*)wq + hh * 64 * 768 + c;
  unsigned wA[64], wB[64], wC[64];
  #pragma unroll
  for (int p = 0; p < 64; ++p) {
    wA[p] = wqp[p * 768];
    wB[p] = wqp[p * 768 + 256];
    wC[p] = wqp[p * 768 + 512];
  }
  const float bR = bhh[c], bZ = bhh[kH + c], bN = bhh[2 * kH + c];
  if (tid < kH / 2) hpk[0][tid] = 0u;
  float h = 0.f;
  __syncthreads();
  const float* gbase = gi + b * 128 * 768 + c;
  for (int t = 0; t < 128; ++t) {
    const float* g = gbase + t * 768;
    const float gA = g[0], gB = g[256], gC = g[512];
    float aR0 = 0.f, aR1 = 0.f, aZ0 = 0.f, aZ1 = 0.f, aN0 = 0.f, aN1 = 0.f;
    const unsigned* hb = hpk[t & 1] + hh * 64;
    #pragma unroll
    for (int q = 0; q < 16; ++q) {
      const uint4 hp = *reinterpret_cast<const uint4*>(hb + 4 * q);
      aR0 = dot2(wA[4 * q + 0], hp.x, aR0);
      aZ0 = dot2(wB[4 * q + 0], hp.x, aZ0);
      aN0 = dot2(wC[4 * q + 0], hp.x, aN0);
      aR1 = dot2(wA[4 * q + 1], hp.y, aR1);
      aZ1 = dot2(wB[4 * q + 1], hp.y, aZ1);
      aN1 = dot2(wC[4 * q + 1], hp.y, aN1);
      aR0 = dot2(wA[4 * q + 2], hp.z, aR0);
      aZ0 = dot2(wB[4 * q + 2], hp.z, aZ0);
      aN0 = dot2(wC[4 * q + 2], hp.z, aN0);
      aR1 = dot2(wA[4 * q + 3], hp.w, aR1);
      aZ1 = dot2(wB[4 * q + 3], hp.w, aZ1);
      aN1 = dot2(wC[4 * q + 3], hp.w, aN1);
    }
    float aR = aR0 + aR1; aR += __shfl_xor(aR, 1, 64);
    float aZ = aZ0 + aZ1; aZ += __shfl_xor(aZ, 1, 64);
    float aN = aN0 + aN1; aN += __shfl_xor(aN, 1, 64);
    const float r = fsig(gA + bR + aR);
    const float z = fsig(gB + bZ + aZ);
    const float n = ftanh(fmaf(r, aN + bN, gC));
    h = (1.f - z) * n + z * h;
    if (hh == 0) reinterpret_cast<__half*>(hpk[(t + 1) & 1])[c] = __float2half(h);
    else sout[(b * 128 + t) * kH + c] = h;
    __syncthreads();
  }
}

// ---------------- sfuse/sgate, 16 rows per block ----------------------------------
__global__ __launch_bounds__(256) void k_fsgate(
    const float* __restrict__ s1, const float* __restrict__ fsw,
    const float* __restrict__ fsb, const float* __restrict__ gw,
    const float* __restrict__ gb, float* __restrict__ sfuse,
    float* __restrict__ sgate) {
  __shared__ float sr[16][kH], sf[16][kH];
  const int bw0 = blockIdx.x * 16, tid = threadIdx.x;
  for (int i = tid; i < 16 * kH; i += 256) sr[i >> 8][i & 255] = s1[bw0 * kH + i];
  __syncthreads();
  float acc[16];
  {
    const float bb = fsb[tid];
    #pragma unroll
    for (int r = 0; r < 16; ++r) acc[r] = bb;
  }
  #pragma unroll 2
  for (int k = 0; k < kH; ++k) {
    const float w = fsw[k * kH + tid];
    #pragma unroll
    for (int r = 0; r < 16; ++r) acc[r] = fmaf(sr[r][k], w, acc[r]);
  }
  #pragma unroll
  for (int r = 0; r < 16; ++r) { sf[r][tid] = acc[r]; sfuse[(bw0 + r) * kH + tid] = acc[r]; }
  __syncthreads();
  {
    const float bb = gb[tid];
    #pragma unroll
    for (int r = 0; r < 16; ++r) acc[r] = bb;
  }
  #pragma unroll 2
  for (int k = 0; k < kH; ++k) {
    const float w = gw[(kH + k) * kH + tid];
    #pragma unroll
    for (int r = 0; r < 16; ++r) acc[r] = fmaf(sf[r][k], w, acc[r]);
  }
  #pragma unroll
  for (int r = 0; r < 16; ++r) sgate[(bw0 + r) * kH + tid] = acc[r];
}

// ================= fused GNN + gate + decoder (MFMA bf16, 8 waves) ================
// R9 geometry EXACTLY (BSTR=136/GSTR=264: every LDS row 16B-aligned so bs8
// reads stay single ds_read_b128 — R11's 132/260 broke alignment, 2x LDS ops,
// 367->708 us; its 2-way bank aliasing is hidden under idle time, m136).
// NEW: tag B-fragment double-buffer — hipcc drains vmcnt(0) at every
// __syncthreads, so per-phase L2 weight loads re-paid full latency after each
// barrier. Issue phase s+1's 4 fragments BEFORE propb: latency overlaps the
// propagation compute, barrier-drain completes them. +32 VGPR (64->~96 < 128).

constexpr int BSTR = 136;               // buf row stride (ushorts, 272B: 16B-aligned)
constexpr int GSTR = 264;               // GT row stride (ushorts, 528B: 16B-aligned)
constexpr int SB0 = 0;
constexpr int SB1 = 36 * BSTR;          // 4896
constexpr int S_TOT = 2 * 36 * BSTR;    // 9792 ushorts (GT 36x264=9504 fits)

// dst(rows<33) = P @ src, bf16 pairs (512-thread grid-stride)
DEV void propb(ushortT* __restrict__ dst, const ushortT* __restrict__ src,
               const int* __restrict__ rp, const int* __restrict__ cs,
               const float* __restrict__ cn) {
  for (int idx = threadIdx.x; idx < kN * 64; idx += 512) {
    const int n = idx >> 6, j2 = idx & 63;
    float a0 = 0.f, a1 = 0.f;
    const int p1 = rp[n + 1];
    for (int p = rp[n]; p < p1; ++p) {
      const unsigned v = *(const unsigned*)(src + cs[p] * BSTR + 2 * j2);
      const float w = cn[p];
      a0 = fmaf(__uint_as_float(v << 16), w, a0);
      a1 = fmaf(__uint_as_float(v & 0xffff0000u), w, a1);
    }
    *(unsigned*)(dst + n * BSTR + 2 * j2) = (unsigned)f2bf(a0) | ((unsigned)f2bf(a1) << 16);
  }
}

// tag pass: buf0(h) -> buf0(out), ping-pong with buf1. W stacked 4x[col][k].
// B-fragments double-buffered across the propb/barrier boundary.
template <bool RELU>
DEV void tag_mfma(ushortT* __restrict__ Sb, const ushortT* __restrict__ WT,
                  const float* __restrict__ b, const int* __restrict__ rp,
                  const int* __restrict__ cs, const float* __restrict__ cn,
                  int wv, int lane) {
  const int lr = lane & 15, lg = lane >> 4;
  const int col = wv * 16 + lr;
  f32x4 acc[3];
  #pragma unroll
  for (int i = 0; i < 3; ++i) acc[i] = (f32x4){0.f, 0.f, 0.f, 0.f};
  bs8 bbuf[4];
  #pragma unroll
  for (int ks = 0; ks < 4; ++ks)
    bbuf[ks] = ldb(WT + (col << 7) + ks * 32 + lg * 8);
  #pragma unroll
  for (int s = 0; s < 4; ++s) {
    const ushortT* A = Sb + ((s & 1) ? SB1 : SB0);
    ushortT* Bn      = Sb + ((s & 1) ? SB0 : SB1);
    #pragma unroll
    for (int ks = 0; ks < 4; ++ks) {
      const int kof = ks * 32 + lg * 8;
      bs8 a0 = ldb(A + (lr) * BSTR + kof);
      bs8 a1 = ldb(A + (16 + lr) * BSTR + kof);
      bs8 a2 = ldb(A + (32 + lr) * BSTR + kof);
      acc[0] = mfma16(a0, bbuf[ks], acc[0]);
      acc[1] = mfma16(a1, bbuf[ks], acc[1]);
      acc[2] = mfma16(a2, bbuf[ks], acc[2]);
    }
    if (s < 3) {
      // prefetch next phase's B-fragments: in flight during propb, completed
      // by the barrier's vmcnt(0) drain.
      bs8 nbuf[4];
      #pragma unroll
      for (int ks = 0; ks < 4; ++ks)
        nbuf[ks] = ldb(WT + ((s + 1) << 14) + (col << 7) + ks * 32 + lg * 8);
      propb(Bn, A, rp, cs, cn);
      __syncthreads();
      #pragma unroll
      for (int ks = 0; ks < 4; ++ks) bbuf[ks] = nbuf[ks];
    }
  }
  __syncthreads();  // all s=3 A-reads complete before overwriting buf0
  const float bias = b[col];
  #pragma unroll
  for (int mt = 0; mt < 3; ++mt)
    #pragma unroll
    for (int r = 0; r < 4; ++r) {
      const int row = mt * 16 + lg * 4 + r;
      if (row < kN) {
        float x = acc[mt][r] + bias;
        if (RELU) x = fmaxf(x, 0.f);
        (Sb + SB0)[row * BSTR + col] = f2bf(x);
      }
    }
  __syncthreads();
}

__global__ __launch_bounds__(512, 4) void k_fused(
    const float* __restrict__ feat_seq, const float* __restrict__ x_wls,
    const float* __restrict__ pre_w, const float* __restrict__ pre_b,
    const float* __restrict__ tb1, const float* __restrict__ tb2,
    const float* __restrict__ d1b, const float* __restrict__ d2w,
    const float* __restrict__ d2b, const float* __restrict__ ws,
    const float* __restrict__ sfuse, const float* __restrict__ sgate,
    float* __restrict__ out) {
  __shared__ __align__(16) ushortT S[S_TOT];
  __shared__ float sfrow[kH], sgrow[kH];
  __shared__ float xw[2 * kN];
  __shared__ float featl[kF];
  __shared__ int rp[kN + 1], cs[kE];
  __shared__ float cn[kE];
  __shared__ float part[8][48][2];
  const int tid = threadIdx.x, bw = blockIdx.x;
  const int wv = tid >> 6, lane = tid & 63;
  const int lr = lane & 15, lg = lane >> 4;
  const ushortT* WB = (const ushortT*)(ws + OFF_GI);
  ushortT* GT = S;  // 36 rows x 264, overlaps buf0+buf1

  if (tid < kH) sfrow[tid] = sfuse[bw * kH + tid];
  else if (tid < 2 * kH) sgrow[tid - kH] = sgate[bw * kH + (tid - kH)];
  if (tid < 2 * kN) xw[tid] = x_wls[bw * 2 * kN + tid];
  else if (tid >= 66 && tid < 66 + kF) featl[tid - 66] = feat_seq[bw * kF + (tid - 66)];
  if (tid >= 128 && tid < 128 + kN + 1) rp[tid - 128] = ((const int*)(ws + OFF_ROWPTR))[tid - 128];
  if (tid >= 192 && tid < 256) {
    cs[tid - 192] = ((const int*)(ws + OFF_COLSRC))[tid - 192];
    cn[tid - 192] = ws[OFF_COLNORM + (tid - 192)];
  }
  // zero pad rows 33..35 of buf0 and buf1 (full BSTR-col rows)
  if (tid < 3 * BSTR) {
    S[SB0 + kN * BSTR + tid] = 0;
    S[SB1 + kN * BSTR + tid] = 0;
  }
  __syncthreads();

  // gin = [feat(8), va, vm] @ pre_w + pre_b  -> buf0 (33x128 bf16)
  for (int idx = tid; idx < kN * kGH; idx += 512) {
    const int n = idx >> 7, j = idx & 127;
    float a = pre_b[j];
    #pragma unroll
    for (int f = 0; f < kF; ++f) a = fmaf(featl[f], pre_w[f * kGH + j], a);
    a = fmaf(xw[n], pre_w[8 * kGH + j], a);
    a = fmaf(xw[kN + n], pre_w[9 * kGH + j], a);
    S[SB0 + n * BSTR + j] = f2bf(a);
  }
  __syncthreads();

  tag_mfma<true >(S, WB + WB_TW1, tb1, rp, cs, cn, wv, lane);
  tag_mfma<false>(S, WB + WB_TW2, tb2, rp, cs, cn, wv, lane);

  // ---- g_t = G @ Wc + c -> GT (33x256 bf16), regs then overwrite ----
  {
    f32x4 acc[6];
    #pragma unroll
    for (int i = 0; i < 6; ++i) acc[i] = (f32x4){0.f, 0.f, 0.f, 0.f};
    #pragma unroll
    for (int ks = 0; ks < 4; ++ks) {
      const int kof = ks * 32 + lg * 8;
      bs8 a0 = ldb(S + SB0 + (lr) * BSTR + kof);
      bs8 a1 = ldb(S + SB0 + (16 + lr) * BSTR + kof);
      bs8 a2 = ldb(S + SB0 + (32 + lr) * BSTR + kof);
      #pragma unroll
      for (int nt = 0; nt < 2; ++nt) {
        const int col = (wv * 2 + nt) * 16 + lr;
        bs8 bb = ldb(WB + WB_WC + (col << 7) + kof);
        acc[0 + nt] = mfma16(a0, bb, acc[0 + nt]);
        acc[2 + nt] = mfma16(a1, bb, acc[2 + nt]);
        acc[4 + nt] = mfma16(a2, bb, acc[4 + nt]);
      }
    }
    __syncthreads();  // all buf reads done; S becomes GT
    #pragma unroll
    for (int mt = 0; mt < 3; ++mt)
      #pragma unroll
      for (int nt = 0; nt < 2; ++nt) {
        const int col = (wv * 2 + nt) * 16 + lr;
        const float cb = ws[OFF_C + col];
        const f32x4 v = acc[mt * 2 + nt];
        #pragma unroll
        for (int r = 0; r < 4; ++r) {
          const int row = mt * 16 + lg * 4 + r;
          if (row < kN) GT[row * GSTR + col] = f2bf(v[r] + cb);
        }
      }
    __syncthreads();
  }

  // ---- gate: alpha = sigmoid(GT @ gate_w + sgate); U = a*gt + (1-a)*sfuse -> GT --
  {
    f32x4 acc[6];
    #pragma unroll
    for (int i = 0; i < 6; ++i) acc[i] = (f32x4){0.f, 0.f, 0.f, 0.f};
    #pragma unroll 2
    for (int ks = 0; ks < 8; ++ks) {
      const int kof = ks * 32 + lg * 8;
      const int r2 = (32 + lr) < 36 ? (32 + lr) : 35;  // clamp: GT has 36 rows
      bs8 a0 = ldb(GT + (lr) * GSTR + kof);
      bs8 a1 = ldb(GT + (16 + lr) * GSTR + kof);
      bs8 a2 = ldb(GT + r2 * GSTR + kof);
      #pragma unroll
      for (int nt = 0; nt < 2; ++nt) {
        const int col = (wv * 2 + nt) * 16 + lr;
        bs8 bb = ldb(WB + WB_GATE + (col << 8) + kof);
        acc[0 + nt] = mfma16(a0, bb, acc[0 + nt]);
        acc[2 + nt] = mfma16(a1, bb, acc[2 + nt]);
        acc[4 + nt] = mfma16(a2, bb, acc[4 + nt]);
      }
    }
    // compute U into acc (reads GT), then barrier, then write U over GT
    #pragma unroll
    for (int mt = 0; mt < 3; ++mt)
      #pragma unroll
      for (int nt = 0; nt < 2; ++nt) {
        const int col = (wv * 2 + nt) * 16 + lr;
        const float sg = sgrow[col], sf = sfrow[col];
        #pragma unroll
        for (int r = 0; r < 4; ++r) {
          const int row = mt * 16 + lg * 4 + r;
          if (row < kN) {
            const float al = fsig(acc[mt * 2 + nt][r] + sg);
            const float gt = bf2f(GT[row * GSTR + col]);
            acc[mt * 2 + nt][r] = al * gt + (1.f - al) * sf;
          }
        }
      }
    __syncthreads();
    #pragma unroll
    for (int mt = 0; mt < 3; ++mt)
      #pragma unroll
      for (int nt = 0; nt < 2; ++nt) {
        const int col = (wv * 2 + nt) * 16 + lr;
        #pragma unroll
        for (int r = 0; r < 4; ++r) {
          const int row = mt * 16 + lg * 4 + r;
          if (row < kN) GT[row * GSTR + col] = f2bf(acc[mt * 2 + nt][r]);
        }
      }
    __syncthreads();
  }

  // ---- d1: V = relu(U @ d1w + d1b); d2 (256->2) + residual ----
  {
    f32x4 acc[6];
    #pragma unroll
    for (int i = 0; i < 6; ++i) acc[i] = (f32x4){0.f, 0.f, 0.f, 0.f};
    #pragma unroll 2
    for (int ks = 0; ks < 8; ++ks) {
      const int kof = ks * 32 + lg * 8;
      const int r2 = (32 + lr) < 36 ? (32 + lr) : 35;
      bs8 a0 = ldb(GT + (lr) * GSTR + kof);
      bs8 a1 = ldb(GT + (16 + lr) * GSTR + kof);
      bs8 a2 = ldb(GT + r2 * GSTR + kof);
      #pragma unroll
      for (int nt = 0; nt < 2; ++nt) {
        const int col = (wv * 2 + nt) * 16 + lr;
        bs8 bb = ldb(WB + WB_D1 + (col << 8) + kof);
        acc[0 + nt] = mfma16(a0, bb, acc[0 + nt]);
        acc[2 + nt] = mfma16(a1, bb, acc[2 + nt]);
        acc[4 + nt] = mfma16(a2, bb, acc[4 + nt]);
      }
    }
    float p0[3][4], p1[3][4];
    #pragma unroll
    for (int mt = 0; mt < 3; ++mt)
      #pragma unroll
      for (int r = 0; r < 4; ++r) { p0[mt][r] = 0.f; p1[mt][r] = 0.f; }
    #pragma unroll
    for (int nt = 0; nt < 2; ++nt) {
      const int col = (wv * 2 + nt) * 16 + lr;
      const float db = d1b[col];
      const float2 dp = *reinterpret_cast<const float2*>(d2w + col * 2);
      #pragma unroll
      for (int mt = 0; mt < 3; ++mt)
        #pragma unroll
        for (int r = 0; r < 4; ++r) {
          const float v = fmaxf(acc[mt * 2 + nt][r] + db, 0.f);
          p0[mt][r] = fmaf(v, dp.x, p0[mt][r]);
          p1[mt][r] = fmaf(v, dp.y, p1[mt][r]);
        }
    }
    #pragma unroll
    for (int mt = 0; mt < 3; ++mt)
      #pragma unroll
      for (int r = 0; r < 4; ++r) {
        #pragma unroll
        for (int off = 1; off < 16; off <<= 1) {
          p0[mt][r] += __shfl_xor(p0[mt][r], off, 64);
          p1[mt][r] += __shfl_xor(p1[mt][r], off, 64);
        }
      }
    if (lr == 0) {
      #pragma unroll
      for (int mt = 0; mt < 3; ++mt)
        #pragma unroll
        for (int r = 0; r < 4; ++r) {
          const int row = mt * 16 + lg * 4 + r;
          part[wv][row][0] = p0[mt][r];
          part[wv][row][1] = p1[mt][r];
        }
    }
    __syncthreads();
    if (tid < 66) {
      const int c = tid >= 33 ? 1 : 0;
      const int n = tid - 33 * c;
      float s = d2b[c];
      #pragma unroll
      for (int w = 0; w < 8; ++w) s += part[w][n][c];
      out[bw * 66 + tid] = xw[tid] + s;
    }
  }
}

extern "C" void kernel_launch(void* const* d_in, const int* in_sizes, int n_in,
                              void* d_out, int out_size, void* d_ws, size_t ws_size,
                              hipStream_t stream) {
  const float* r_seq  = (const float*)d_in[0];
  const float* feat   = (const float*)d_in[1];
  const float* x_wls  = (const float*)d_in[2];
  const int*   eidx   = (const int*)d_in[3];
  const float* ew     = (const float*)d_in[4];
  const float* pre_w  = (const float*)d_in[5];
  const float* pre_b  = (const float*)d_in[6];
  const float* tag_w1 = (const float*)d_in[7];
  const float* tag_b1 = (const float*)d_in[8];
  const float* tag_w2 = (const float*)d_in[9];
  const float* tag_b2 = (const float*)d_in[10];
  const float* post_w = (const float*)d_in[11];
  const float* post_b = (const float*)d_in[12];
  const float* tp_w1  = (const float*)d_in[13];
  const float* tp_b1  = (const float*)d_in[14];
  const float* tp_w2  = (const float*)d_in[15];
  const float* tp_b2  = (const float*)d_in[16];
  const float* wih0   = (const float*)d_in[17];
  const float* whh0   = (const float*)d_in[18];
  const float* bih0   = (const float*)d_in[19];
  const float* bhh0   = (const float*)d_in[20];
  const float* wih1   = (const float*)d_in[21];
  const float* whh1   = (const float*)d_in[22];
  const float* bih1   = (const float*)d_in[23];
  const float* bhh1   = (const float*)d_in[24];
  const float* fg_w   = (const float*)d_in[25];
  const float* fg_b   = (const float*)d_in[26];
  const float* fs_w   = (const float*)d_in[27];
  const float* fs_b   = (const float*)d_in[28];
  const float* gate_w = (const float*)d_in[29];
  const float* gate_b = (const float*)d_in[30];
  const float* d1_w   = (const float*)d_in[31];
  const float* d1_b   = (const float*)d_in[32];
  const float* d2_w   = (const float*)d_in[33];
  const float* d2_b   = (const float*)d_in[34];
  float* ws = (float*)d_ws;
  float* outp = (float*)d_out;

  k_prep<<<1, 64, 0, stream>>>(eidx, ew, ws);
  k_wcfold<<<kGH + 1, kH, 0, stream>>>(post_w, post_b, fg_w, fg_b, ws);
  k_wq<<<768, 256, 0, stream>>>(whh0, whh1, ws);
  k_tpmlp<<<kBW / 16, 256, 0, stream>>>(r_seq, x_wls, tp_w1, tp_b1, tp_w2, tp_b2,
                                        ws + OFF_SPRE);
  k_gigemm<<<kBW / 16, 768, 0, stream>>>(ws + OFF_SPRE, wih0, bih0, ws + OFF_GI);
  k_scan<<<32, 512, 0, stream>>>(ws + OFF_GI, ws + OFF_WQ0, bhh0, ws + OFF_SPRE);
  k_gigemm<<<kBW / 16, 768, 0, stream>>>(ws + OFF_SPRE, wih1, bih1, ws + OFF_GI);
  k_scan<<<32, 512, 0, stream>>>(ws + OFF_GI, ws + OFF_WQ1, bhh1, ws + OFF_SPRE);
  // GI region is now dead -> bf16 B-fragment weights for k_fused
  k_wprep<<<(WB_TOT + 255) / 256, 256, 0, stream>>>(tag_w1, tag_w2, gate_w, d1_w, ws);
  k_fsgate<<<kBW / 16, 256, 0, stream>>>(ws + OFF_SPRE, fs_w, fs_b, gate_w, gate_b,
                                         ws + OFF_SFUSE, ws + OFF_SGATE);
  k_fused<<<kBW, 512, 0, stream>>>(feat, x_wls, pre_w, pre_b, tag_b1, tag_b2,
                                   d1_b, d2_w, d2_b, ws, ws + OFF_SFUSE,
                                   ws + OFF_SGATE, outp);
}

// Round 13
// 966.971 us; speedup vs baseline: 1.4383x; 1.0115x over previous
//
#include <hip/hip_runtime.h>
#include <hip/hip_fp16.h>
#include <cmath>

#define DEV __device__ __forceinline__

typedef unsigned short ushortT;
typedef short bs8 __attribute__((ext_vector_type(8)));
typedef float f32x4 __attribute__((ext_vector_type(4)));
typedef _Float16 f16x2 __attribute__((ext_vector_type(2)));

constexpr int kBW = 4096;          // B*W
constexpr int kM = 100, kF = 8, kN = 33, kH = 256, kGH = 128, kE = 64;

// ws offsets (in floats)
constexpr int OFF_ROWPTR  = 0;       // 34 int
constexpr int OFF_COLSRC  = 64;      // 64 int
constexpr int OFF_COLNORM = 128;     // 64 f
constexpr int OFF_C       = 192;     // 256 f (folded bias)
constexpr int OFF_WC      = 512;     // 128*256 f (post_w@fg_w)
constexpr int OFF_SPRE    = 33280;               // 4096*256 (s_pre -> s0 -> s1)
constexpr int OFF_GI      = OFF_SPRE + kBW * kH; // 4096*768 f
constexpr int OFF_SFUSE   = OFF_GI + kBW * 3 * kH;  // 4096*256 f
constexpr int OFF_SGATE   = OFF_SFUSE + kBW * kH;   // 4096*256 f
// scan weights (f16 pairs) live in SFUSE region (dead until k_fsgate):
constexpr int OFF_WQ0     = OFF_SFUSE;            // 98304 u32
constexpr int OFF_WQ1     = OFF_SFUSE + 98304;    // 98304 u32
// bf16 B-fragment weights for k_fused live in GI region (dead after scans):
constexpr int WB_TW1  = 0;        // 4*128*128
constexpr int WB_TW2  = 65536;    // 4*128*128
constexpr int WB_WC   = 131072;   // 256 cols x 128 k
constexpr int WB_GATE = 163840;   // 256 cols x 256 k
constexpr int WB_D1   = 229376;   // 256 cols x 256 k
constexpr int WB_TOT  = 294912;

DEV float frcp(float x) { return __builtin_amdgcn_rcpf(x); }
DEV float fsig(float x) { return frcp(1.0f + __expf(-x)); }
DEV float ftanh(float x) { float e = __expf(2.0f * x); return 1.0f - 2.0f * frcp(e + 1.0f); }

DEV ushortT f2bf(float x) {
  unsigned u = __float_as_uint(x);
  unsigned r = u + 0x7fffu + ((u >> 16) & 1u);
  return (ushortT)(r >> 16);
}
DEV float bf2f(ushortT u) { return __uint_as_float(((unsigned)u) << 16); }

DEV f32x4 mfma16(bs8 a, bs8 b, f32x4 c) {
  return __builtin_amdgcn_mfma_f32_16x16x32_bf16(a, b, c, 0, 0, 0);
}
DEV bs8 ldb(const ushortT* p) { return *reinterpret_cast<const bs8*>(p); }

#if __has_builtin(__builtin_amdgcn_fdot2)
DEV float dot2(unsigned w, unsigned hp, float acc) {
  f16x2 wv = __builtin_bit_cast(f16x2, w);
  f16x2 hv = __builtin_bit_cast(f16x2, hp);
  return __builtin_amdgcn_fdot2(wv, hv, acc, false);
}
#else
DEV float dot2(unsigned w, unsigned hp, float acc) {
  f16x2 wv = __builtin_bit_cast(f16x2, w);
  f16x2 hv = __builtin_bit_cast(f16x2, hp);
  acc = fmaf((float)wv.x, (float)hv.x, acc);
  acc = fmaf((float)wv.y, (float)hv.y, acc);
  return acc;
}
#endif

// ---------------- graph prep: degree norm + CSR by dst ---------------------------
__global__ void k_prep(const int* __restrict__ ei, const float* __restrict__ ew,
                       float* __restrict__ ws) {
  if (blockIdx.x != 0 || threadIdx.x != 0) return;
  int* rowptr = (int*)(ws + OFF_ROWPTR);
  int* colsrc = (int*)(ws + OFF_COLSRC);
  float* colnorm = ws + OFF_COLNORM;
  const int* src = ei;
  const int* dst = ei + kE;
  float deg[kN]; int cnt[kN];
  for (int n = 0; n < kN; ++n) { deg[n] = 0.f; cnt[n] = 0; }
  for (int e = 0; e < kE; ++e) { deg[dst[e]] += ew[e]; cnt[dst[e]]++; }
  float dinv[kN];
  for (int n = 0; n < kN; ++n) dinv[n] = deg[n] > 0.f ? 1.0f / sqrtf(deg[n]) : 0.f;
  int pos[kN];
  int run = 0;
  for (int n = 0; n < kN; ++n) { rowptr[n] = run; pos[n] = run; run += cnt[n]; }
  rowptr[kN] = run;
  for (int e = 0; e < kE; ++e) {
    int d = dst[e];
    int p = pos[d]++;
    colsrc[p] = src[e];
    colnorm[p] = dinv[src[e]] * ew[e] * dinv[d];
  }
}

// ---------------- fold Wc = post_w @ fg_w (128x256), c = post_b @ fg_w + fg_b -----
__global__ void k_wcfold(const float* __restrict__ post_w, const float* __restrict__ post_b,
                         const float* __restrict__ fg_w, const float* __restrict__ fg_b,
                         float* __restrict__ ws) {
  const int j = threadIdx.x;
  if ((int)blockIdx.x < kGH) {
    const int k = blockIdx.x;
    float a = 0.f;
    #pragma unroll 4
    for (int m = 0; m < kH; ++m) a = fmaf(post_w[k * kH + m], fg_w[m * kH + j], a);
    ws[OFF_WC + k * kH + j] = a;
  } else {
    float a = fg_b[j];
    #pragma unroll 4
    for (int m = 0; m < kH; ++m) a = fmaf(post_b[m], fg_w[m * kH + j], a);
    ws[OFF_C + j] = a;
  }
}

// ---------------- scan weights: whh[k][j] -> f16 pairs wq[(k/2)*768 + j] ----------
__global__ void k_wq(const float* __restrict__ w0, const float* __restrict__ w1,
                     float* __restrict__ ws) {
  const int idx = blockIdx.x * 256 + threadIdx.x;
  if (idx >= 2 * 98304) return;
  const int layer = idx / 98304;
  const int rem = idx - layer * 98304;
  const int p = rem / 768, j = rem - p * 768;
  const float* w = layer ? w1 : w0;
  unsigned* dst = (unsigned*)(ws + (layer ? OFF_WQ1 : OFF_WQ0));
  __half2 v = __floats2half2_rn(w[(2 * p) * 768 + j], w[(2 * p + 1) * 768 + j]);
  dst[rem] = *reinterpret_cast<unsigned*>(&v);
}

// ---------------- bf16 B-fragment weights ([col][k]) for k_fused -----------------
__global__ void k_wprep(const float* __restrict__ tw1, const float* __restrict__ tw2,
                        const float* __restrict__ gatew, const float* __restrict__ d1w,
                        float* __restrict__ ws) {
  const int idx = blockIdx.x * 256 + threadIdx.x;
  if (idx >= WB_TOT) return;
  ushortT* WB = (ushortT*)(ws + OFF_GI);
  float v; int dst;
  if (idx < 65536) {
    int s = idx >> 14, r = idx & 16383, k = r >> 7, col = r & 127;
    v = tw1[(s << 14) + (k << 7) + col]; dst = WB_TW1 + (s << 14) + (col << 7) + k;
  } else if (idx < 131072) {
    int i = idx - 65536; int s = i >> 14, r = i & 16383, k = r >> 7, col = r & 127;
    v = tw2[(s << 14) + (k << 7) + col]; dst = WB_TW2 + (s << 14) + (col << 7) + k;
  } else if (idx < 163840) {
    int i = idx - 131072; int k = i & 127, col = i >> 7;
    v = ws[OFF_WC + (k << 8) + col]; dst = WB_WC + (col << 7) + k;
  } else if (idx < 229376) {
    int i = idx - 163840; int k = i & 255, col = i >> 8;
    v = gatew[(k << 8) + col]; dst = WB_GATE + (col << 8) + k;
  } else {
    int i = idx - 229376; int k = i & 255, col = i >> 8;
    v = d1w[(k << 8) + col]; dst = WB_D1 + (col << 8) + k;
  }
  WB[dst] = f2bf(v);
}

// ---------------- temporal pre-MLP, 16 rows per block -----------------------------
__global__ __launch_bounds__(256) void k_tpmlp(
    const float* __restrict__ r_seq, const float* __restrict__ x_wls,
    const float* __restrict__ w1, const float* __restrict__ b1,
    const float* __restrict__ w2, const float* __restrict__ b2,
    float* __restrict__ sout) {
  __shared__ float inr[16][kM + 2 * kN];  // 16 x 166
  __shared__ float h1[16][kH];
  const int bw0 = blockIdx.x * 16, tid = threadIdx.x;
  #pragma unroll
  for (int r = 0; r < 16; ++r) {
    for (int c = tid; c < kM + 2 * kN; c += 256)
      inr[r][c] = (c < kM) ? r_seq[(bw0 + r) * kM + c]
                           : x_wls[(bw0 + r) * 2 * kN + (c - kM)];
  }
  __syncthreads();
  float acc[16];
  {
    const float bb = b1[tid];
    #pragma unroll
    for (int r = 0; r < 16; ++r) acc[r] = bb;
  }
  for (int k = 0; k < kM + 2 * kN; ++k) {
    const float w = w1[k * kH + tid];
    #pragma unroll
    for (int r = 0; r < 16; ++r) acc[r] = fmaf(inr[r][k], w, acc[r]);
  }
  #pragma unroll
  for (int r = 0; r < 16; ++r) h1[r][tid] = fmaxf(acc[r], 0.f);
  __syncthreads();
  {
    const float bb = b2[tid];
    #pragma unroll
    for (int r = 0; r < 16; ++r) acc[r] = bb;
  }
  #pragma unroll 2
  for (int k = 0; k < kH; ++k) {
    const float w = w2[k * kH + tid];
    #pragma unroll
    for (int r = 0; r < 16; ++r) acc[r] = fmaf(h1[r][k], w, acc[r]);
  }
  #pragma unroll
  for (int r = 0; r < 16; ++r) sout[(bw0 + r) * kH + tid] = fmaxf(acc[r], 0.f);
}

// ---------------- gi = s @ wih + bih, 16 rows per block ---------------------------
__global__ __launch_bounds__(768) void k_gigemm(
    const float* __restrict__ sin, const float* __restrict__ wih,
    const float* __restrict__ bih, float* __restrict__ gi) {
  __shared__ float sr[16][kH];
  const int bw0 = blockIdx.x * 16, tid = threadIdx.x;
  for (int i = tid; i < 16 * kH; i += 768) sr[i >> 8][i & 255] = sin[bw0 * kH + i];
  __syncthreads();
  float acc[16];
  {
    const float bb = bih[tid];
    #pragma unroll
    for (int r = 0; r < 16; ++r) acc[r] = bb;
  }
  #pragma unroll 2
  for (int k = 0; k < kH; ++k) {
    const float w = wih[k * 768 + tid];
    #pragma unroll
    for (int r = 0; r < 16; ++r) acc[r] = fmaf(sr[r][k], w, acc[r]);
  }
  #pragma unroll
  for (int r = 0; r < 16; ++r) gi[(bw0 + r) * 768 + tid] = acc[r];
}

// ---------------- GRU scan: pair-split cols, weights in VGPRs, gi pipelined -------
// R9 structure + NEW: next-step gi loads issued BEFORE the dot loop (gi is
// 12.6 MB — exceeds per-XCD L2, written on other XCDs, so per-step loads pay
// ~200-900 cyc mostly unhidden; one-step-ahead prefetch hides it under the
// dots + barrier of the current step). +6 regs (cap 256, demand ~230).
__global__ __launch_bounds__(512, 2) void k_scan(
    const float* __restrict__ gi, const float* __restrict__ wq,
    const float* __restrict__ bhh, float* __restrict__ sout) {
  __shared__ __align__(16) unsigned hpk[2][kH / 2];
  const int b = blockIdx.x, tid = threadIdx.x;
  const int c = tid >> 1, hh = tid & 1;
  const unsigned* wqp = (const unsigned*)wq + hh * 64 * 768 + c;
  unsigned wA[64], wB[64], wC[64];
  #pragma unroll
  for (int p = 0; p < 64; ++p) {
    wA[p] = wqp[p * 768];
    wB[p] = wqp[p * 768 + 256];
    wC[p] = wqp[p * 768 + 512];
  }
  const float bR = bhh[c], bZ = bhh[kH + c], bN = bhh[2 * kH + c];
  if (tid < kH / 2) hpk[0][tid] = 0u;
  float h = 0.f;
  __syncthreads();
  const float* gbase = gi + b * 128 * 768 + c;
  float gA = gbase[0], gB = gbase[256], gC = gbase[512];
  for (int t = 0; t < 128; ++t) {
    // issue next step's gi loads now; they complete during dots+barrier.
    const float* gn = gbase + (t < 127 ? (t + 1) : 127) * 768;
    const float nA = gn[0], nB = gn[256], nC = gn[512];
    float aR0 = 0.f, aR1 = 0.f, aZ0 = 0.f, aZ1 = 0.f, aN0 = 0.f, aN1 = 0.f;
    const unsigned* hb = hpk[t & 1] + hh * 64;
    #pragma unroll
    for (int q = 0; q < 16; ++q) {
      const uint4 hp = *reinterpret_cast<const uint4*>(hb + 4 * q);
      aR0 = dot2(wA[4 * q + 0], hp.x, aR0);
      aZ0 = dot2(wB[4 * q + 0], hp.x, aZ0);
      aN0 = dot2(wC[4 * q + 0], hp.x, aN0);
      aR1 = dot2(wA[4 * q + 1], hp.y, aR1);
      aZ1 = dot2(wB[4 * q + 1], hp.y, aZ1);
      aN1 = dot2(wC[4 * q + 1], hp.y, aN1);
      aR0 = dot2(wA[4 * q + 2], hp.z, aR0);
      aZ0 = dot2(wB[4 * q + 2], hp.z, aZ0);
      aN0 = dot2(wC[4 * q + 2], hp.z, aN0);
      aR1 = dot2(wA[4 * q + 3], hp.w, aR1);
      aZ1 = dot2(wB[4 * q + 3], hp.w, aZ1);
      aN1 = dot2(wC[4 * q + 3], hp.w, aN1);
    }
    float aR = aR0 + aR1; aR += __shfl_xor(aR, 1, 64);
    float aZ = aZ0 + aZ1; aZ += __shfl_xor(aZ, 1, 64);
    float aN = aN0 + aN1; aN += __shfl_xor(aN, 1, 64);
    const float r = fsig(gA + bR + aR);
    const float z = fsig(gB + bZ + aZ);
    const float n = ftanh(fmaf(r, aN + bN, gC));
    h = (1.f - z) * n + z * h;
    if (hh == 0) reinterpret_cast<__half*>(hpk[(t + 1) & 1])[c] = __float2half(h);
    else sout[(b * 128 + t) * kH + c] = h;
    gA = nA; gB = nB; gC = nC;
    __syncthreads();
  }
}

// ---------------- sfuse/sgate, 16 rows per block ----------------------------------
__global__ __launch_bounds__(256) void k_fsgate(
    const float* __restrict__ s1, const float* __restrict__ fsw,
    const float* __restrict__ fsb, const float* __restrict__ gw,
    const float* __restrict__ gb, float* __restrict__ sfuse,
    float* __restrict__ sgate) {
  __shared__ float sr[16][kH], sf[16][kH];
  const int bw0 = blockIdx.x * 16, tid = threadIdx.x;
  for (int i = tid; i < 16 * kH; i += 256) sr[i >> 8][i & 255] = s1[bw0 * kH + i];
  __syncthreads();
  float acc[16];
  {
    const float bb = fsb[tid];
    #pragma unroll
    for (int r = 0; r < 16; ++r) acc[r] = bb;
  }
  #pragma unroll 2
  for (int k = 0; k < kH; ++k) {
    const float w = fsw[k * kH + tid];
    #pragma unroll
    for (int r = 0; r < 16; ++r) acc[r] = fmaf(sr[r][k], w, acc[r]);
  }
  #pragma unroll
  for (int r = 0; r < 16; ++r) { sf[r][tid] = acc[r]; sfuse[(bw0 + r) * kH + tid] = acc[r]; }
  __syncthreads();
  {
    const float bb = gb[tid];
    #pragma unroll
    for (int r = 0; r < 16; ++r) acc[r] = bb;
  }
  #pragma unroll 2
  for (int k = 0; k < kH; ++k) {
    const float w = gw[(kH + k) * kH + tid];
    #pragma unroll
    for (int r = 0; r < 16; ++r) acc[r] = fmaf(sf[r][k], w, acc[r]);
  }
  #pragma unroll
  for (int r = 0; r < 16; ++r) sgate[(bw0 + r) * kH + tid] = acc[r];
}

// ================= fused GNN + gate + decoder (MFMA bf16, 8 waves) ================
// EXACT R9 structure (best measured: 367 us). BSTR=136/GSTR=264 keep rows
// 16B-aligned (single ds_read_b128; R11's conflict-free strides broke this).
// No b-frag prefetch (R12: compiler spilled it to scratch, +100MB writes).

constexpr int BSTR = 136;               // buf row stride (ushorts, 272B)
constexpr int GSTR = 264;               // GT row stride (ushorts, 528B)
constexpr int SB0 = 0;
constexpr int SB1 = 36 * BSTR;          // 4896
constexpr int S_TOT = 2 * 36 * BSTR;    // 9792 ushorts (GT 36x264=9504 fits)

// dst(rows<33) = P @ src, bf16 pairs (512-thread grid-stride)
DEV void propb(ushortT* __restrict__ dst, const ushortT* __restrict__ src,
               const int* __restrict__ rp, const int* __restrict__ cs,
               const float* __restrict__ cn) {
  for (int idx = threadIdx.x; idx < kN * 64; idx += 512) {
    const int n = idx >> 6, j2 = idx & 63;
    float a0 = 0.f, a1 = 0.f;
    const int p1 = rp[n + 1];
    for (int p = rp[n]; p < p1; ++p) {
      const unsigned v = *(const unsigned*)(src + cs[p] * BSTR + 2 * j2);
      const float w = cn[p];
      a0 = fmaf(__uint_as_float(v << 16), w, a0);
      a1 = fmaf(__uint_as_float(v & 0xffff0000u), w, a1);
    }
    *(unsigned*)(dst + n * BSTR + 2 * j2) = (unsigned)f2bf(a0) | ((unsigned)f2bf(a1) << 16);
  }
}

// tag pass: buf0(h) -> buf0(out), ping-pong with buf1. W stacked 4x[col][k].
template <bool RELU>
DEV void tag_mfma(ushortT* __restrict__ Sb, const ushortT* __restrict__ WT,
                  const float* __restrict__ b, const int* __restrict__ rp,
                  const int* __restrict__ cs, const float* __restrict__ cn,
                  int wv, int lane) {
  const int lr = lane & 15, lg = lane >> 4;
  const int col = wv * 16 + lr;
  f32x4 acc[3];
  #pragma unroll
  for (int i = 0; i < 3; ++i) acc[i] = (f32x4){0.f, 0.f, 0.f, 0.f};
  #pragma unroll
  for (int s = 0; s < 4; ++s) {
    const ushortT* A = Sb + ((s & 1) ? SB1 : SB0);
    ushortT* Bn      = Sb + ((s & 1) ? SB0 : SB1);
    #pragma unroll
    for (int ks = 0; ks < 4; ++ks) {
      const int kof = ks * 32 + lg * 8;
      bs8 a0 = ldb(A + (lr) * BSTR + kof);
      bs8 a1 = ldb(A + (16 + lr) * BSTR + kof);
      bs8 a2 = ldb(A + (32 + lr) * BSTR + kof);
      bs8 bb = ldb(WT + (s << 14) + (col << 7) + kof);
      acc[0] = mfma16(a0, bb, acc[0]);
      acc[1] = mfma16(a1, bb, acc[1]);
      acc[2] = mfma16(a2, bb, acc[2]);
    }
    if (s < 3) {
      propb(Bn, A, rp, cs, cn);
      __syncthreads();
    }
  }
  __syncthreads();  // all s=3 A-reads complete before overwriting buf0
  const float bias = b[col];
  #pragma unroll
  for (int mt = 0; mt < 3; ++mt)
    #pragma unroll
    for (int r = 0; r < 4; ++r) {
      const int row = mt * 16 + lg * 4 + r;
      if (row < kN) {
        float x = acc[mt][r] + bias;
        if (RELU) x = fmaxf(x, 0.f);
        (Sb + SB0)[row * BSTR + col] = f2bf(x);
      }
    }
  __syncthreads();
}

__global__ __launch_bounds__(512, 4) void k_fused(
    const float* __restrict__ feat_seq, const float* __restrict__ x_wls,
    const float* __restrict__ pre_w, const float* __restrict__ pre_b,
    const float* __restrict__ tb1, const float* __restrict__ tb2,
    const float* __restrict__ d1b, const float* __restrict__ d2w,
    const float* __restrict__ d2b, const float* __restrict__ ws,
    const float* __restrict__ sfuse, const float* __restrict__ sgate,
    float* __restrict__ out) {
  __shared__ __align__(16) ushortT S[S_TOT];
  __shared__ float sfrow[kH], sgrow[kH];
  __shared__ float xw[2 * kN];
  __shared__ float featl[kF];
  __shared__ int rp[kN + 1], cs[kE];
  __shared__ float cn[kE];
  __shared__ float part[8][48][2];
  const int tid = threadIdx.x, bw = blockIdx.x;
  const int wv = tid >> 6, lane = tid & 63;
  const int lr = lane & 15, lg = lane >> 4;
  const ushortT* WB = (const ushortT*)(ws + OFF_GI);
  ushortT* GT = S;  // 36 rows x 264, overlaps buf0+buf1

  if (tid < kH) sfrow[tid] = sfuse[bw * kH + tid];
  else if (tid < 2 * kH) sgrow[tid - kH] = sgate[bw * kH + (tid - kH)];
  if (tid < 2 * kN) xw[tid] = x_wls[bw * 2 * kN + tid];
  else if (tid >= 66 && tid < 66 + kF) featl[tid - 66] = feat_seq[bw * kF + (tid - 66)];
  if (tid >= 128 && tid < 128 + kN + 1) rp[tid - 128] = ((const int*)(ws + OFF_ROWPTR))[tid - 128];
  if (tid >= 192 && tid < 256) {
    cs[tid - 192] = ((const int*)(ws + OFF_COLSRC))[tid - 192];
    cn[tid - 192] = ws[OFF_COLNORM + (tid - 192)];
  }
  // zero pad rows 33..35 of buf0 and buf1 (full BSTR-col rows)
  if (tid < 3 * BSTR) {
    S[SB0 + kN * BSTR + tid] = 0;
    S[SB1 + kN * BSTR + tid] = 0;
  }
  __syncthreads();

  // gin = [feat(8), va, vm] @ pre_w + pre_b  -> buf0 (33x128 bf16)
  for (int idx = tid; idx < kN * kGH; idx += 512) {
    const int n = idx >> 7, j = idx & 127;
    float a = pre_b[j];
    #pragma unroll
    for (int f = 0; f < kF; ++f) a = fmaf(featl[f], pre_w[f * kGH + j], a);
    a = fmaf(xw[n], pre_w[8 * kGH + j], a);
    a = fmaf(xw[kN + n], pre_w[9 * kGH + j], a);
    S[SB0 + n * BSTR + j] = f2bf(a);
  }
  __syncthreads();

  tag_mfma<true >(S, WB + WB_TW1, tb1, rp, cs, cn, wv, lane);
  tag_mfma<false>(S, WB + WB_TW2, tb2, rp, cs, cn, wv, lane);

  // ---- g_t = G @ Wc + c -> GT (33x256 bf16), regs then overwrite ----
  {
    f32x4 acc[6];
    #pragma unroll
    for (int i = 0; i < 6; ++i) acc[i] = (f32x4){0.f, 0.f, 0.f, 0.f};
    #pragma unroll
    for (int ks = 0; ks < 4; ++ks) {
      const int kof = ks * 32 + lg * 8;
      bs8 a0 = ldb(S + SB0 + (lr) * BSTR + kof);
      bs8 a1 = ldb(S + SB0 + (16 + lr) * BSTR + kof);
      bs8 a2 = ldb(S + SB0 + (32 + lr) * BSTR + kof);
      #pragma unroll
      for (int nt = 0; nt < 2; ++nt) {
        const int col = (wv * 2 + nt) * 16 + lr;
        bs8 bb = ldb(WB + WB_WC + (col << 7) + kof);
        acc[0 + nt] = mfma16(a0, bb, acc[0 + nt]);
        acc[2 + nt] = mfma16(a1, bb, acc[2 + nt]);
        acc[4 + nt] = mfma16(a2, bb, acc[4 + nt]);
      }
    }
    __syncthreads();  // all buf reads done; S becomes GT
    #pragma unroll
    for (int mt = 0; mt < 3; ++mt)
      #pragma unroll
      for (int nt = 0; nt < 2; ++nt) {
        const int col = (wv * 2 + nt) * 16 + lr;
        const float cb = ws[OFF_C + col];
        const f32x4 v = acc[mt * 2 + nt];
        #pragma unroll
        for (int r = 0; r < 4; ++r) {
          const int row = mt * 16 + lg * 4 + r;
          if (row < kN) GT[row * GSTR + col] = f2bf(v[r] + cb);
        }
      }
    __syncthreads();
  }

  // ---- gate: alpha = sigmoid(GT @ gate_w + sgate); U = a*gt + (1-a)*sfuse -> GT --
  {
    f32x4 acc[6];
    #pragma unroll
    for (int i = 0; i < 6; ++i) acc[i] = (f32x4){0.f, 0.f, 0.f, 0.f};
    #pragma unroll 2
    for (int ks = 0; ks < 8; ++ks) {
      const int kof = ks * 32 + lg * 8;
      const int r2 = (32 + lr) < 36 ? (32 + lr) : 35;  // clamp: GT has 36 rows
      bs8 a0 = ldb(GT + (lr) * GSTR + kof);
      bs8 a1 = ldb(GT + (16 + lr) * GSTR + kof);
      bs8 a2 = ldb(GT + r2 * GSTR + kof);
      #pragma unroll
      for (int nt = 0; nt < 2; ++nt) {
        const int col = (wv * 2 + nt) * 16 + lr;
        bs8 bb = ldb(WB + WB_GATE + (col << 8) + kof);
        acc[0 + nt] = mfma16(a0, bb, acc[0 + nt]);
        acc[2 + nt] = mfma16(a1, bb, acc[2 + nt]);
        acc[4 + nt] = mfma16(a2, bb, acc[4 + nt]);
      }
    }
    // compute U into acc (reads GT), then barrier, then write U over GT
    #pragma unroll
    for (int mt = 0; mt < 3; ++mt)
      #pragma unroll
      for (int nt = 0; nt < 2; ++nt) {
        const int col = (wv * 2 + nt) * 16 + lr;
        const float sg = sgrow[col], sf = sfrow[col];
        #pragma unroll
        for (int r = 0; r < 4; ++r) {
          const int row = mt * 16 + lg * 4 + r;
          if (row < kN) {
            const float al = fsig(acc[mt * 2 + nt][r] + sg);
            const float gt = bf2f(GT[row * GSTR + col]);
            acc[mt * 2 + nt][r] = al * gt + (1.f - al) * sf;
          }
        }
      }
    __syncthreads();
    #pragma unroll
    for (int mt = 0; mt < 3; ++mt)
      #pragma unroll
      for (int nt = 0; nt < 2; ++nt) {
        const int col = (wv * 2 + nt) * 16 + lr;
        #pragma unroll
        for (int r = 0; r < 4; ++r) {
          const int row = mt * 16 + lg * 4 + r;
          if (row < kN) GT[row * GSTR + col] = f2bf(acc[mt * 2 + nt][r]);
        }
      }
    __syncthreads();
  }

  // ---- d1: V = relu(U @ d1w + d1b); d2 (256->2) + residual ----
  {
    f32x4 acc[6];
    #pragma unroll
    for (int i = 0; i < 6; ++i) acc[i] = (f32x4){0.f, 0.f, 0.f, 0.f};
    #pragma unroll 2
    for (int ks = 0; ks < 8; ++ks) {
      const int kof = ks * 32 + lg * 8;
      const int r2 = (32 + lr) < 36 ? (32 + lr) : 35;
      bs8 a0 = ldb(GT + (lr) * GSTR + kof);
      bs8 a1 = ldb(GT + (16 + lr) * GSTR + kof);
      bs8 a2 = ldb(GT + r2 * GSTR + kof);
      #pragma unroll
      for (int nt = 0; nt < 2; ++nt) {
        const int col = (wv * 2 + nt) * 16 + lr;
        bs8 bb = ldb(WB + WB_D1 + (col << 8) + kof);
        acc[0 + nt] = mfma16(a0, bb, acc[0 + nt]);
        acc[2 + nt] = mfma16(a1, bb, acc[2 + nt]);
        acc[4 + nt] = mfma16(a2, bb, acc[4 + nt]);
      }
    }
    float p0[3][4], p1[3][4];
    #pragma unroll
    for (int mt = 0; mt < 3; ++mt)
      #pragma unroll
      for (int r = 0; r < 4; ++r) { p0[mt][r] = 0.f; p1[mt][r] = 0.f; }
    #pragma unroll
    for (int nt = 0; nt < 2; ++nt) {
      const int col = (wv * 2 + nt) * 16 + lr;
      const float db = d1b[col];
      const float2 dp = *reinterpret_cast<const float2*>(d2w + col * 2);
      #pragma unroll
      for (int mt = 0; mt < 3; ++mt)
        #pragma unroll
        for (int r = 0; r < 4; ++r) {
          const float v = fmaxf(acc[mt * 2 + nt][r] + db, 0.f);
          p0[mt][r] = fmaf(v, dp.x, p0[mt][r]);
          p1[mt][r] = fmaf(v, dp.y, p1[mt][r]);
        }
    }
    #pragma unroll
    for (int mt = 0; mt < 3; ++mt)
      #pragma unroll
      for (int r = 0; r < 4; ++r) {
        #pragma unroll
        for (int off = 1; off < 16; off <<= 1) {
          p0[mt][r] += __shfl_xor(p0[mt][r], off, 64);
          p1[mt][r] += __shfl_xor(p1[mt][r], off, 64);
        }
      }
    if (lr == 0) {
      #pragma unroll
      for (int mt = 0; mt < 3; ++mt)
        #pragma unroll
        for (int r = 0; r < 4; ++r) {
          const int row = mt * 16 + lg * 4 + r;
          part[wv][row][0] = p0[mt][r];
          part[wv][row][1] = p1[mt][r];
        }
    }
    __syncthreads();
    if (tid < 66) {
      const int c = tid >= 33 ? 1 : 0;
      const int n = tid - 33 * c;
      float s = d2b[c];
      #pragma unroll
      for (int w = 0; w < 8; ++w) s += part[w][n][c];
      out[bw * 66 + tid] = xw[tid] + s;
    }
  }
}

extern "C" void kernel_launch(void* const* d_in, const int* in_sizes, int n_in,
                              void* d_out, int out_size, void* d_ws, size_t ws_size,
                              hipStream_t stream) {
  const float* r_seq  = (const float*)d_in[0];
  const float* feat   = (const float*)d_in[1];
  const float* x_wls  = (const float*)d_in[2];
  const int*   eidx   = (const int*)d_in[3];
  const float* ew     = (const float*)d_in[4];
  const float* pre_w  = (const float*)d_in[5];
  const float* pre_b  = (const float*)d_in[6];
  const float* tag_w1 = (const float*)d_in[7];
  const float* tag_b1 = (const float*)d_in[8];
  const float* tag_w2 = (const float*)d_in[9];
  const float* tag_b2 = (const float*)d_in[10];
  const float* post_w = (const float*)d_in[11];
  const float* post_b = (const float*)d_in[12];
  const float* tp_w1  = (const float*)d_in[13];
  const float* tp_b1  = (const float*)d_in[14];
  const float* tp_w2  = (const float*)d_in[15];
  const float* tp_b2  = (const float*)d_in[16];
  const float* wih0   = (const float*)d_in[17];
  const float* whh0   = (const float*)d_in[18];
  const float* bih0   = (const float*)d_in[19];
  const float* bhh0   = (const float*)d_in[20];
  const float* wih1   = (const float*)d_in[21];
  const float* whh1   = (const float*)d_in[22];
  const float* bih1   = (const float*)d_in[23];
  const float* bhh1   = (const float*)d_in[24];
  const float* fg_w   = (const float*)d_in[25];
  const float* fg_b   = (const float*)d_in[26];
  const float* fs_w   = (const float*)d_in[27];
  const float* fs_b   = (const float*)d_in[28];
  const float* gate_w = (const float*)d_in[29];
  const float* gate_b = (const float*)d_in[30];
  const float* d1_w   = (const float*)d_in[31];
  const float* d1_b   = (const float*)d_in[32];
  const float* d2_w   = (const float*)d_in[33];
  const float* d2_b   = (const float*)d_in[34];
  float* ws = (float*)d_ws;
  float* outp = (float*)d_out;

  k_prep<<<1, 64, 0, stream>>>(eidx, ew, ws);
  k_wcfold<<<kGH + 1, kH, 0, stream>>>(post_w, post_b, fg_w, fg_b, ws);
  k_wq<<<768, 256, 0, stream>>>(whh0, whh1, ws);
  k_tpmlp<<<kBW / 16, 256, 0, stream>>>(r_seq, x_wls, tp_w1, tp_b1, tp_w2, tp_b2,
                                        ws + OFF_SPRE);
  k_gigemm<<<kBW / 16, 768, 0, stream>>>(ws + OFF_SPRE, wih0, bih0, ws + OFF_GI);
  k_scan<<<32, 512, 0, stream>>>(ws + OFF_GI, ws + OFF_WQ0, bhh0, ws + OFF_SPRE);
  k_gigemm<<<kBW / 16, 768, 0, stream>>>(ws + OFF_SPRE, wih1, bih1, ws + OFF_GI);
  k_scan<<<32, 512, 0, stream>>>(ws + OFF_GI, ws + OFF_WQ1, bhh1, ws + OFF_SPRE);
  // GI region is now dead -> bf16 B-fragment weights for k_fused
  k_wprep<<<(WB_TOT + 255) / 256, 256, 0, stream>>>(tag_w1, tag_w2, gate_w, d1_w, ws);
  k_fsgate<<<kBW / 16, 256, 0, stream>>>(ws + OFF_SPRE, fs_w, fs_b, gate_w, gate_b,
                                         ws + OFF_SFUSE, ws + OFF_SGATE);
  k_fused<<<kBW, 512, 0, stream>>>(feat, x_wls, pre_w, pre_b, tag_b1, tag_b2,
                                   d1_b, d2_w, d2_b, ws, ws + OFF_SFUSE,
                                   ws + OFF_SGATE, outp);
}